// Round 1
// baseline (4235.970 us; speedup 1.0000x reference)
//
#include <hip/hip_runtime.h>
#include <hip/hip_bf16.h>
#include <math.h>

// Problem constants
#define BB 4
#define NN 1024
#define TT 16
#define FIN 32
#define HH 128      // H1 == H2 == 128
#define LH 64
#define MLPH 32
#define NEG (-9e15f)

__device__ __forceinline__ float elu2(float v) {
    v = v > 0.f ? v : (expf(v) - 1.f);
    v = v > 0.f ? v : (expf(v) - 1.f);
    return v;
}

// ---------------- precompute: score vectors, transposed LSTM weights ----------------
__global__ void k_pre(const float* __restrict__ W1, const float* __restrict__ a1,
                      const float* __restrict__ W2, const float* __restrict__ a2,
                      const float* __restrict__ W_ih, const float* __restrict__ W_hh,
                      const float* __restrict__ b_ih, const float* __restrict__ b_hh,
                      float* va1s, float* va1d, float* va2s, float* va2d,
                      float* WihT, float* WhhT, float* bsum) {
    int tid = threadIdx.x;
    if (tid < FIN) {
        float s = 0.f, d = 0.f;
        for (int c = 0; c < HH; ++c) { float w = W1[tid * HH + c]; s += w * a1[c]; d += w * a1[HH + c]; }
        va1s[tid] = s; va1d[tid] = d;
    }
    if (tid < HH) {
        float s = 0.f, d = 0.f;
        for (int c = 0; c < HH; ++c) { float w = W2[tid * HH + c]; s += w * a2[c]; d += w * a2[HH + c]; }
        va2s[tid] = s; va2d[tid] = d;
    }
    for (int idx = tid; idx < 256 * 128; idx += blockDim.x) {
        int g = idx >> 7, k = idx & 127;
        WihT[k * 256 + g] = W_ih[idx];
    }
    for (int idx = tid; idx < 256 * 64; idx += blockDim.x) {
        int g = idx >> 6, k = idx & 63;
        WhhT[k * 256 + g] = W_hh[idx];
    }
    if (tid < 256) bsum[tid] = b_ih[tid] + b_hh[tid];
}

// ---------------- GAT layer 1 projection: Wh = x_t @ W1, plus rank-1 scores ----------------
__global__ __launch_bounds__(256) void k_proj1(const float* __restrict__ x, const float* __restrict__ W1,
                                               const float* __restrict__ va1s, const float* __restrict__ va1d,
                                               float* __restrict__ Wh, float* __restrict__ ssrc,
                                               float* __restrict__ sdst) {
    __shared__ float xs[2][FIN];
    int bt = blockIdx.x >> 9;            // N/2 = 512 blocks per (b,t)
    int n0 = (blockIdx.x & 511) << 1;
    int b = bt >> 4, t = bt & 15;
    int tid = threadIdx.x;
    if (tid < 64) {
        int r = tid >> 5, k = tid & 31;
        xs[r][k] = x[((size_t)((b << 10) + n0 + r) * TT + t) * FIN + k];
    }
    __syncthreads();
    int r = tid >> 7, c = tid & 127;
    float acc = 0.f;
#pragma unroll
    for (int k = 0; k < FIN; ++k) acc += xs[r][k] * W1[k * HH + c];
    Wh[((size_t)(bt << 10) + n0 + r) * HH + c] = acc;
    if (c < 2) {
        const float* v = c ? va1d : va1s;
        float s = 0.f;
#pragma unroll
        for (int k = 0; k < FIN; ++k) s += xs[r][k] * v[k];
        (c ? sdst : ssrc)[(bt << 10) + n0 + r] = s;
    }
}

// ---------------- GAT layer 2 projection: Wh = h1 @ W2, plus rank-1 scores ----------------
__global__ __launch_bounds__(256) void k_proj2(const float* __restrict__ hin, const float* __restrict__ W2,
                                               const float* __restrict__ va2s, const float* __restrict__ va2d,
                                               float* __restrict__ Wh, float* __restrict__ ssrc,
                                               float* __restrict__ sdst) {
    __shared__ float hs[2][HH];
    int bt = blockIdx.x >> 9;
    int n0 = (blockIdx.x & 511) << 1;
    int tid = threadIdx.x;
    {
        int r = tid >> 7, k = tid & 127;
        hs[r][k] = hin[((size_t)(bt << 10) + n0 + r) * HH + k];
    }
    __syncthreads();
    int r = tid >> 7, c = tid & 127;
    float acc = 0.f;
#pragma unroll 4
    for (int k = 0; k < HH; ++k) acc += hs[r][k] * W2[k * HH + c];
    Wh[((size_t)(bt << 10) + n0 + r) * HH + c] = acc;
    if (c < 2) {
        const float* v = c ? va2d : va2s;
        float s = 0.f;
#pragma unroll 4
        for (int k = 0; k < HH; ++k) s += hs[r][k] * v[k];
        (c ? sdst : ssrc)[(bt << 10) + n0 + r] = s;
    }
}

// ---------------- attention: softmax(mask(lrelu(s_i+s_j))) @ Wh, double-ELU ----------------
__global__ __launch_bounds__(256) void k_attn(const float* __restrict__ Wh, const float* __restrict__ ssrc,
                                              const float* __restrict__ sdst, const int* __restrict__ adj,
                                              float* __restrict__ hout) {
    __shared__ float p[4 * NN];          // 16 KB: 4 rows of scores
    int bt = blockIdx.x >> 8;            // 256 blocks per (b,t)
    int i0 = (blockIdx.x & 255) << 2;
    int b = bt >> 4;
    int tid = threadIdx.x;
    const float* ss = ssrc + (bt << 10);
    const float* sd = sdst + (bt << 10);
    const int* A = adj + ((size_t)b << 20);

    for (int idx = tid; idx < 4 * NN; idx += 256) {
        int r = idx >> 10, j = idx & 1023;
        int i = i0 + r;
        float e = ss[i] + sd[j];
        e = e > 0.f ? e : 0.2f * e;
        p[idx] = (A[((size_t)i << 10) + j] > 0) ? e : NEG;
    }
    __syncthreads();

    int w = tid >> 6, lane = tid & 63;
    float* pr = p + (w << 10);
    float m = -3.4e38f;
    for (int j = lane; j < NN; j += 64) m = fmaxf(m, pr[j]);
#pragma unroll
    for (int o = 32; o > 0; o >>= 1) m = fmaxf(m, __shfl_xor(m, o));
    float s = 0.f;
    for (int j = lane; j < NN; j += 64) { float v = expf(pr[j] - m); pr[j] = v; s += v; }
#pragma unroll
    for (int o = 32; o > 0; o >>= 1) s += __shfl_xor(s, o);
    float inv = 1.f / s;

    const float* WhB = Wh + ((size_t)bt << 17);
    const float2* Wp = (const float2*)WhB + lane;   // columns (2*lane, 2*lane+1)
    float a0 = 0.f, a1v = 0.f;
    for (int j = 0; j < NN; j += 4) {
        float4 pv = *(const float4*)&pr[j];
        float2 v0 = Wp[(size_t)(j + 0) * 64];
        float2 v1 = Wp[(size_t)(j + 1) * 64];
        float2 v2 = Wp[(size_t)(j + 2) * 64];
        float2 v3 = Wp[(size_t)(j + 3) * 64];
        a0  += pv.x * v0.x + pv.y * v1.x + pv.z * v2.x + pv.w * v3.x;
        a1v += pv.x * v0.y + pv.y * v1.y + pv.z * v2.y + pv.w * v3.y;
    }
    a0 = elu2(a0 * inv);
    a1v = elu2(a1v * inv);
    int i = i0 + w;
    float* outp = hout + ((size_t)((bt << 10) + i)) * HH + 2 * lane;
    outp[0] = a0;
    outp[1] = a1v;
}

// ---------------- LSTM over T + fused output MLP ----------------
__global__ __launch_bounds__(512) void k_lstm(const float* __restrict__ g, const float* __restrict__ WihT,
                                              const float* __restrict__ WhhT, const float* __restrict__ bsum,
                                              const float* __restrict__ Wo1, const float* __restrict__ bo1,
                                              const float* __restrict__ Wo2, const float* __restrict__ bo2,
                                              float* __restrict__ out) {
    __shared__ float xt[16][HH];
    __shared__ float hs[16][LH];
    __shared__ float cs[16][LH];
    __shared__ float gs[16][256];
    __shared__ float hid[16][MLPH];
    int tid = threadIdx.x;
    int m0 = blockIdx.x * 16;
    int b = m0 >> 10, n0 = m0 & 1023;

    for (int idx = tid; idx < 16 * LH; idx += 512) { ((float*)hs)[idx] = 0.f; ((float*)cs)[idx] = 0.f; }
    __syncthreads();

    int gg = tid & 255, half = tid >> 8;
    int mbase = half * 8;
    for (int t = 0; t < TT; ++t) {
        for (int idx = tid; idx < 16 * HH; idx += 512) {
            int mm = idx >> 7, k = idx & 127;
            xt[mm][k] = g[((size_t)(((b * TT + t) << 10) + n0 + mm)) * HH + k];
        }
        __syncthreads();
        float acc[8];
        float bz = bsum[gg];
#pragma unroll
        for (int mm = 0; mm < 8; ++mm) acc[mm] = bz;
        for (int k = 0; k < HH; k += 4) {
            float w0 = WihT[(k + 0) * 256 + gg];
            float w1 = WihT[(k + 1) * 256 + gg];
            float w2 = WihT[(k + 2) * 256 + gg];
            float w3 = WihT[(k + 3) * 256 + gg];
#pragma unroll
            for (int mm = 0; mm < 8; ++mm) {
                float4 xv = *(const float4*)&xt[mbase + mm][k];
                acc[mm] += xv.x * w0 + xv.y * w1 + xv.z * w2 + xv.w * w3;
            }
        }
        for (int k = 0; k < LH; k += 4) {
            float w0 = WhhT[(k + 0) * 256 + gg];
            float w1 = WhhT[(k + 1) * 256 + gg];
            float w2 = WhhT[(k + 2) * 256 + gg];
            float w3 = WhhT[(k + 3) * 256 + gg];
#pragma unroll
            for (int mm = 0; mm < 8; ++mm) {
                float4 hv = *(const float4*)&hs[mbase + mm][k];
                acc[mm] += hv.x * w0 + hv.y * w1 + hv.z * w2 + hv.w * w3;
            }
        }
#pragma unroll
        for (int mm = 0; mm < 8; ++mm) gs[mbase + mm][gg] = acc[mm];
        __syncthreads();
        if (tid < 128) {
            int l = tid & 63; int mb = (tid >> 6) * 8;
            for (int mm = mb; mm < mb + 8; ++mm) {
                float iv = gs[mm][l], fv = gs[mm][64 + l], gv = gs[mm][128 + l], ov = gs[mm][192 + l];
                iv = 1.f / (1.f + expf(-iv));
                fv = 1.f / (1.f + expf(-fv));
                ov = 1.f / (1.f + expf(-ov));
                gv = tanhf(gv);
                float cn = fv * cs[mm][l] + iv * gv;
                cs[mm][l] = cn;
                hs[mm][l] = ov * tanhf(cn);
            }
        }
        __syncthreads();
    }
    // fused MLP: relu(h @ Wo1 + bo1) @ Wo2 + bo2
    {
        int mm = tid >> 5, j = tid & 31;
        float s = bo1[j];
#pragma unroll
        for (int l = 0; l < LH; ++l) s += hs[mm][l] * Wo1[l * MLPH + j];
        hid[mm][j] = s > 0.f ? s : 0.f;
    }
    __syncthreads();
    if (tid < 16) {
        float s = bo2[0];
#pragma unroll
        for (int j = 0; j < MLPH; ++j) s += hid[tid][j] * Wo2[j];
        out[m0 + tid] = s;
    }
}

extern "C" void kernel_launch(void* const* d_in, const int* in_sizes, int n_in,
                              void* d_out, int out_size, void* d_ws, size_t ws_size,
                              hipStream_t stream) {
    const float* x    = (const float*)d_in[0];
    const int*   adj  = (const int*)d_in[1];
    const float* W1   = (const float*)d_in[2];
    const float* a1   = (const float*)d_in[3];
    const float* W2   = (const float*)d_in[4];
    const float* a2   = (const float*)d_in[5];
    const float* W_ih = (const float*)d_in[6];
    const float* W_hh = (const float*)d_in[7];
    const float* b_ih = (const float*)d_in[8];
    const float* b_hh = (const float*)d_in[9];
    const float* Wo1  = (const float*)d_in[10];
    const float* bo1  = (const float*)d_in[11];
    const float* Wo2  = (const float*)d_in[12];
    const float* bo2  = (const float*)d_in[13];
    float* out = (float*)d_out;
    float* ws  = (float*)d_ws;

    const size_t BIG = (size_t)BB * TT * NN * HH;   // 8,388,608 floats
    float* WH   = ws;                 // projection output (both layers, reused)
    float* H1B  = ws + BIG;           // layer-1 attn out; then layer-2 attn out (g)
    float* SS   = ws + 2 * BIG;       // s_src  (both layers, reused)
    float* SD   = SS + (size_t)BB * TT * NN;
    float* VA1S = SD + (size_t)BB * TT * NN;
    float* VA1D = VA1S + FIN;
    float* VA2S = VA1D + FIN;
    float* VA2D = VA2S + HH;
    float* WIHT = VA2D + HH;          // 128x256
    float* WHHT = WIHT + 128 * 256;   // 64x256
    float* BS   = WHHT + 64 * 256;    // 256

    k_pre<<<1, 256, 0, stream>>>(W1, a1, W2, a2, W_ih, W_hh, b_ih, b_hh,
                                 VA1S, VA1D, VA2S, VA2D, WIHT, WHHT, BS);
    k_proj1<<<BB * TT * NN / 2, 256, 0, stream>>>(x, W1, VA1S, VA1D, WH, SS, SD);
    k_attn<<<BB * TT * NN / 4, 256, 0, stream>>>(WH, SS, SD, adj, H1B);
    k_proj2<<<BB * TT * NN / 2, 256, 0, stream>>>(H1B, W2, VA2S, VA2D, WH, SS, SD);
    k_attn<<<BB * TT * NN / 4, 256, 0, stream>>>(WH, SS, SD, adj, H1B);
    k_lstm<<<BB * NN / 16, 512, 0, stream>>>(H1B, WIHT, WHHT, BS, Wo1, bo1, Wo2, bo2, out);
}

// Round 2
// 456.581 us; speedup vs baseline: 9.2776x; 9.2776x over previous
//
#include <hip/hip_runtime.h>
#include <hip/hip_bf16.h>
#include <math.h>

#define BB 4
#define NN 1024
#define TT 16
#define FIN 32
#define HH 128
#define LH 64
#define MLPH 32

typedef __attribute__((ext_vector_type(8))) short short8;
typedef __attribute__((ext_vector_type(4))) float f32x4;
typedef unsigned short u16;
typedef unsigned int u32;

__device__ __forceinline__ u16 f2b(float f) {
    union { float f; u32 u; } v; v.f = f;
    u32 u = v.u;
    return (u16)((u + 0x7FFFu + ((u >> 16) & 1u)) >> 16);
}
__device__ __forceinline__ float b2f(u16 h) {
    union { u32 u; float f; } v; v.u = ((u32)h) << 16;
    return v.f;
}

// ---------------- precompute: bf16 weight layouts + fused bias ----------------
__global__ void k_pre(const float* __restrict__ W1, const float* __restrict__ W2,
                      const float* __restrict__ W_ih, const float* __restrict__ W_hh,
                      const float* __restrict__ b_ih, const float* __restrict__ b_hh,
                      u16* W1T, u16* W2T, u16* WihB, u16* WhhB, float* bsum) {
    int tid = threadIdx.x;
    for (int i = tid; i < 128 * 32; i += 256) { int c = i >> 5, k = i & 31; W1T[i] = f2b(W1[k * 128 + c]); }
    for (int i = tid; i < 128 * 128; i += 256) { int c = i >> 7, k = i & 127; W2T[i] = f2b(W2[k * 128 + c]); }
    for (int i = tid; i < 256 * 128; i += 256) WihB[i] = f2b(W_ih[i]);
    for (int i = tid; i < 256 * 64; i += 256) WhhB[i] = f2b(W_hh[i]);
    if (tid < 256) bsum[tid] = b_ih[tid] + b_hh[tid];
}

// ---------------- adjacency -> bitmask (1 bit per edge) ----------------
__global__ __launch_bounds__(256) void k_mask(const int* __restrict__ adj, unsigned long long* __restrict__ bm) {
    int gw = (blockIdx.x * 256 + threadIdx.x) >> 6;
    int lane = threadIdx.x & 63;
    for (int u = gw; u < (BB * NN * NN) / 64; u += 1024) {
        unsigned long long m = __ballot(adj[(size_t)u * 64 + lane] > 0);
        if (lane == 0) bm[u] = m;
    }
}

// ---------------- GAT layer-1 projection (MFMA): x -> Wh1^T bf16 + s vectors ----------------
__global__ __launch_bounds__(256) void k_projA(const float* __restrict__ x, const u16* __restrict__ W1T,
                                               const float* __restrict__ a1,
                                               u16* __restrict__ WhT, float* __restrict__ ssrc,
                                               float* __restrict__ sdst) {
    __shared__ float tile[64][132];
    __shared__ float sA[256];
    int bt = blockIdx.x >> 4, i0 = (blockIdx.x & 15) << 6;
    int b = bt >> 4, t = bt & 15;
    int tid = threadIdx.x, w = tid >> 6, l = tid & 63;
    int lr = l & 15, lg = l >> 4;
    sA[tid] = a1[tid];
    int i = i0 + 16 * w + lr;
    const float* xp = x + ((size_t)((b << 10) + i) * TT + t) * FIN + 8 * lg;
    float4 x0 = *(const float4*)xp;
    float4 x1 = *(const float4*)(xp + 4);
    short8 af;
    af[0] = (short)f2b(x0.x); af[1] = (short)f2b(x0.y); af[2] = (short)f2b(x0.z); af[3] = (short)f2b(x0.w);
    af[4] = (short)f2b(x1.x); af[5] = (short)f2b(x1.y); af[6] = (short)f2b(x1.z); af[7] = (short)f2b(x1.w);
    f32x4 zz = {0.f, 0.f, 0.f, 0.f};
#pragma unroll
    for (int tc = 0; tc < 8; ++tc) {
        short8 bf = *(const short8*)(W1T + ((16 * tc + lr) << 5) + 8 * lg);
        f32x4 d = __builtin_amdgcn_mfma_f32_16x16x32_bf16(af, bf, zz, 0, 0, 0);
#pragma unroll
        for (int r = 0; r < 4; ++r) tile[16 * w + 4 * lg + r][16 * tc + lr] = d[r];
    }
    __syncthreads();
    if (tid < 128) {
        int r = tid & 63;
        const float* av = sA + ((tid < 64) ? 0 : 128);
        float s = 0.f;
#pragma unroll 4
        for (int c = 0; c < 128; ++c) s += tile[r][c] * av[c];
        ((tid < 64) ? ssrc : sdst)[(bt << 10) + i0 + r] = s;
    }
    {
        int c = tid & 127, hh2 = tid >> 7;
        u16 tmp[32];
#pragma unroll
        for (int j = 0; j < 32; ++j) tmp[j] = f2b(tile[32 * hh2 + j][c]);
        u16* dst = WhT + (((size_t)(bt << 7) + c) << 10) + i0 + 32 * hh2;
#pragma unroll
        for (int q = 0; q < 4; ++q) *(short8*)(dst + 8 * q) = *(const short8*)(tmp + 8 * q);
    }
}

// ---------------- GAT layer-2 projection (MFMA): h1 bf16 -> Wh2^T bf16 + s vectors ----------------
__global__ __launch_bounds__(256) void k_projB(const u16* __restrict__ h1, const u16* __restrict__ W2T,
                                               const float* __restrict__ a2,
                                               u16* __restrict__ WhT, float* __restrict__ ssrc,
                                               float* __restrict__ sdst) {
    __shared__ float tile[64][132];
    __shared__ float sA[256];
    int bt = blockIdx.x >> 4, i0 = (blockIdx.x & 15) << 6;
    int tid = threadIdx.x, w = tid >> 6, l = tid & 63;
    int lr = l & 15, lg = l >> 4;
    sA[tid] = a2[tid];
    int i = i0 + 16 * w + lr;
    const u16* ap = h1 + (((size_t)(bt << 10) + i) << 7) + 8 * lg;
    f32x4 acc[8];
#pragma unroll
    for (int tc = 0; tc < 8; ++tc) acc[tc] = (f32x4){0.f, 0.f, 0.f, 0.f};
#pragma unroll
    for (int ch = 0; ch < 4; ++ch) {
        short8 af = *(const short8*)(ap + 32 * ch);
#pragma unroll
        for (int tc = 0; tc < 8; ++tc) {
            short8 bf = *(const short8*)(W2T + ((16 * tc + lr) << 7) + 32 * ch + 8 * lg);
            acc[tc] = __builtin_amdgcn_mfma_f32_16x16x32_bf16(af, bf, acc[tc], 0, 0, 0);
        }
    }
#pragma unroll
    for (int tc = 0; tc < 8; ++tc)
#pragma unroll
        for (int r = 0; r < 4; ++r) tile[16 * w + 4 * lg + r][16 * tc + lr] = acc[tc][r];
    __syncthreads();
    if (tid < 128) {
        int r = tid & 63;
        const float* av = sA + ((tid < 64) ? 0 : 128);
        float s = 0.f;
#pragma unroll 4
        for (int c = 0; c < 128; ++c) s += tile[r][c] * av[c];
        ((tid < 64) ? ssrc : sdst)[(bt << 10) + i0 + r] = s;
    }
    {
        int c = tid & 127, hh2 = tid >> 7;
        u16 tmp[32];
#pragma unroll
        for (int j = 0; j < 32; ++j) tmp[j] = f2b(tile[32 * hh2 + j][c]);
        u16* dst = WhT + (((size_t)(bt << 7) + c) << 10) + i0 + 32 * hh2;
#pragma unroll
        for (int q = 0; q < 4; ++q) *(short8*)(dst + 8 * q) = *(const short8*)(tmp + 8 * q);
    }
}

// ---------------- attention (MFMA flash-style): P built in-register ----------------
__global__ __launch_bounds__(256) void k_attn(const u16* __restrict__ WhT, const float* __restrict__ ssrc,
                                              const float* __restrict__ sdst, const u32* __restrict__ bm,
                                              u16* __restrict__ hout) {
    __shared__ float sd[1024];
    __shared__ u32 bml[64 * 32];
    int bt = blockIdx.x >> 4, i0 = (blockIdx.x & 15) << 6;
    int b = bt >> 4;
    int tid = threadIdx.x, w = tid >> 6, l = tid & 63;
    int lr = l & 15, lg = l >> 4;
    for (int k = tid; k < 1024; k += 256) sd[k] = sdst[(bt << 10) + k];
    for (int k = tid; k < 2048; k += 256) {
        int r = k >> 5, wd = k & 31;
        bml[k] = bm[(((size_t)(b << 10) + i0 + r) << 5) + wd];
    }
    __syncthreads();
    int i = i0 + 16 * w + lr;
    float si = ssrc[(bt << 10) + i];
    const u16* wb = WhT + ((size_t)bt << 17) + ((size_t)lr << 10) + 8 * lg;
    f32x4 acc[8];
#pragma unroll
    for (int tc = 0; tc < 8; ++tc) acc[tc] = (f32x4){0.f, 0.f, 0.f, 0.f};
    float psum = 0.f;
    for (int jc = 0; jc < 32; ++jc) {
        u32 word = bml[((16 * w + lr) << 5) + jc];
        u32 byt = (word >> (8 * lg)) & 0xFFu;
        const float* sdp = sd + 32 * jc + 8 * lg;
        short8 af;
#pragma unroll
        for (int e = 0; e < 8; ++e) {
            float ev = si + sdp[e];
            ev = fmaxf(ev, 0.2f * ev);
            float p = ((byt >> e) & 1u) ? __expf(ev) : 0.f;
            u16 pb = f2b(p);
            af[e] = (short)pb;
            psum += b2f(pb);
        }
#pragma unroll
        for (int tc = 0; tc < 8; ++tc) {
            short8 bf = *(const short8*)(wb + ((size_t)tc << 14) + 32 * jc);
            acc[tc] = __builtin_amdgcn_mfma_f32_16x16x32_bf16(af, bf, acc[tc], 0, 0, 0);
        }
    }
    psum += __shfl_xor(psum, 16);
    psum += __shfl_xor(psum, 32);
    float inv[4];
#pragma unroll
    for (int r = 0; r < 4; ++r) inv[r] = 1.f / __shfl(psum, 4 * lg + r);
    size_t obase = ((size_t)((bt << 10) + i0 + 16 * w)) << 7;
#pragma unroll
    for (int tc = 0; tc < 8; ++tc)
#pragma unroll
        for (int r = 0; r < 4; ++r) {
            float v = acc[tc][r] * inv[r];
            v = v > 0.f ? v : (__expf(v) - 1.f);
            v = v > 0.f ? v : (__expf(v) - 1.f);
            hout[obase + ((size_t)(4 * lg + r) << 7) + 16 * tc + lr] = f2b(v);
        }
}

// ---------------- Gx = seq @ W_ih^T + bias (recurrence-free part), bf16 out ----------------
__global__ __launch_bounds__(256) void k_gx(const u16* __restrict__ g, const u16* __restrict__ WihB,
                                            const float* __restrict__ bsum, u16* __restrict__ Gx) {
    int rm0 = blockIdx.x << 6;
    int bt = rm0 >> 10, n0 = rm0 & 1023;
    int b = bt >> 4, t = bt & 15;
    int tid = threadIdx.x, w = tid >> 6, l = tid & 63;
    int lr = l & 15, lg = l >> 4;
    const u16* ap = g + ((size_t)(rm0 + 16 * w + lr) << 7) + 8 * lg;
    f32x4 acc[16];
#pragma unroll
    for (int tc = 0; tc < 16; ++tc) acc[tc] = (f32x4){0.f, 0.f, 0.f, 0.f};
#pragma unroll
    for (int ch = 0; ch < 4; ++ch) {
        short8 af = *(const short8*)(ap + 32 * ch);
#pragma unroll
        for (int tc = 0; tc < 16; ++tc) {
            short8 bf = *(const short8*)(WihB + ((16 * tc + lr) << 7) + 32 * ch + 8 * lg);
            acc[tc] = __builtin_amdgcn_mfma_f32_16x16x32_bf16(af, bf, acc[tc], 0, 0, 0);
        }
    }
    size_t orow = ((size_t)t << 12) + (b << 10) + n0 + 16 * w;
#pragma unroll
    for (int tc = 0; tc < 16; ++tc) {
        float bz = bsum[16 * tc + lr];
#pragma unroll
        for (int r = 0; r < 4; ++r)
            Gx[((orow + 4 * lg + r) << 8) + 16 * tc + lr] = f2b(acc[tc][r] + bz);
    }
}

// ---------------- LSTM recurrence (MFMA, 16 nodes/block, 1 wave) + fused MLP ----------------
__global__ __launch_bounds__(64, 1) void k_lstm(const u16* __restrict__ Gx, const u16* __restrict__ WhhB,
                                                const float* __restrict__ Wo1, const float* __restrict__ bo1,
                                                const float* __restrict__ Wo2, const float* __restrict__ bo2,
                                                float* __restrict__ out) {
    __shared__ u16 hls[16 * 72];
    __shared__ float hf[16 * 65];
    __shared__ float wo1[64 * 32];
    __shared__ float wo2[32];
    int m0 = blockIdx.x << 4;
    int l = threadIdx.x, lr = l & 15, lg = l >> 4;
    for (int k = l; k < 64 * 32; k += 64) wo1[k] = Wo1[k];
    if (l < 32) wo2[l] = Wo2[l];
    for (int k = l; k < 16 * 72; k += 64) hls[k] = 0;
    short8 bh[16][2];
#pragma unroll
    for (int tc = 0; tc < 16; ++tc)
#pragma unroll
        for (int ch = 0; ch < 2; ++ch)
            bh[tc][ch] = *(const short8*)(WhhB + ((16 * tc + lr) << 6) + 32 * ch + 8 * lg);
    float cst[4][4], hreg[4][4];
#pragma unroll
    for (int r = 0; r < 4; ++r)
#pragma unroll
        for (int q = 0; q < 4; ++q) cst[r][q] = 0.f;
    __syncthreads();
    for (int t = 0; t < TT; ++t) {
        f32x4 acc[16];
        size_t gbase = (((size_t)t << 12) + m0) << 8;
#pragma unroll
        for (int tc = 0; tc < 16; ++tc)
#pragma unroll
            for (int r = 0; r < 4; ++r)
                acc[tc][r] = b2f(Gx[gbase + ((size_t)(4 * lg + r) << 8) + 16 * tc + lr]);
#pragma unroll
        for (int ch = 0; ch < 2; ++ch) {
            short8 af = *(const short8*)(hls + lr * 72 + 32 * ch + 8 * lg);
#pragma unroll
            for (int tc = 0; tc < 16; ++tc)
                acc[tc] = __builtin_amdgcn_mfma_f32_16x16x32_bf16(af, bh[tc][ch], acc[tc], 0, 0, 0);
        }
#pragma unroll
        for (int r = 0; r < 4; ++r)
#pragma unroll
            for (int q = 0; q < 4; ++q) {
                float iv = acc[q][r], fv = acc[q + 4][r], gv = acc[q + 8][r], ov = acc[q + 12][r];
                iv = 1.f / (1.f + __expf(-iv));
                fv = 1.f / (1.f + __expf(-fv));
                ov = 1.f / (1.f + __expf(-ov));
                gv = tanhf(gv);
                float cn = fv * cst[r][q] + iv * gv;
                cst[r][q] = cn;
                hreg[r][q] = ov * tanhf(cn);
            }
        __syncthreads();
#pragma unroll
        for (int r = 0; r < 4; ++r)
#pragma unroll
            for (int q = 0; q < 4; ++q)
                hls[(4 * lg + r) * 72 + 16 * q + lr] = f2b(hreg[r][q]);
        __syncthreads();
    }
#pragma unroll
    for (int r = 0; r < 4; ++r)
#pragma unroll
        for (int q = 0; q < 4; ++q)
            hf[(4 * lg + r) * 65 + 16 * q + lr] = hreg[r][q];
    __syncthreads();
    {
        int r = l & 15, p = l >> 4;
        float hid[8];
#pragma unroll
        for (int q = 0; q < 8; ++q) hid[q] = bo1[8 * p + q];
        for (int j = 0; j < 64; ++j) {
            float hv = hf[r * 65 + j];
#pragma unroll
            for (int q = 0; q < 8; ++q) hid[q] += hv * wo1[j * 32 + 8 * p + q];
        }
        float po = 0.f;
#pragma unroll
        for (int q = 0; q < 8; ++q) po += fmaxf(hid[q], 0.f) * wo2[8 * p + q];
        po += __shfl_xor(po, 16);
        po += __shfl_xor(po, 32);
        if (p == 0) out[m0 + r] = po + bo2[0];
    }
}

extern "C" void kernel_launch(void* const* d_in, const int* in_sizes, int n_in,
                              void* d_out, int out_size, void* d_ws, size_t ws_size,
                              hipStream_t stream) {
    const float* x    = (const float*)d_in[0];
    const int*   adj  = (const int*)d_in[1];
    const float* W1   = (const float*)d_in[2];
    const float* a1   = (const float*)d_in[3];
    const float* W2   = (const float*)d_in[4];
    const float* a2   = (const float*)d_in[5];
    const float* W_ih = (const float*)d_in[6];
    const float* W_hh = (const float*)d_in[7];
    const float* b_ih = (const float*)d_in[8];
    const float* b_hh = (const float*)d_in[9];
    const float* Wo1  = (const float*)d_in[10];
    const float* bo1  = (const float*)d_in[11];
    const float* Wo2  = (const float*)d_in[12];
    const float* bo2  = (const float*)d_in[13];
    float* out = (float*)d_out;

    char* w = (char*)d_ws;
    const size_t SLOT = (size_t)8388608 * sizeof(u16);   // 16.78 MB
    u16* A  = (u16*)w;
    u16* Bf = (u16*)(w + SLOT);
    u16* C  = (u16*)(w + 2 * SLOT);
    char* sm = w + 3 * SLOT;
    float* s1s = (float*)sm;
    float* s1d = s1s + 65536;
    float* s2s = s1d + 65536;
    float* s2d = s2s + 65536;
    u32* BM  = (u32*)(s2d + 65536);      // 131072 words (512 KB)
    u16* W1T = (u16*)(BM + 131072);      // 4096
    u16* W2T = W1T + 4096;               // 16384
    u16* WihB = W2T + 16384;             // 32768
    u16* WhhB = WihB + 32768;            // 16384
    float* BS = (float*)(WhhB + 16384);  // 256
    u16* Gx = Bf;                        // spans Bf..C (33.55 MB), used after both are dead

    k_pre<<<1, 256, 0, stream>>>(W1, W2, W_ih, W_hh, b_ih, b_hh, W1T, W2T, WihB, WhhB, BS);
    k_mask<<<256, 256, 0, stream>>>(adj, (unsigned long long*)BM);
    k_projA<<<1024, 256, 0, stream>>>(x, W1T, a1, A, s1s, s1d);
    k_attn<<<1024, 256, 0, stream>>>(A, s1s, s1d, BM, Bf);
    k_projB<<<1024, 256, 0, stream>>>(Bf, W2T, a2, C, s2s, s2d);
    k_attn<<<1024, 256, 0, stream>>>(C, s2s, s2d, BM, A);
    k_gx<<<1024, 256, 0, stream>>>(A, WihB, BS, Gx);
    k_lstm<<<256, 64, 0, stream>>>(Gx, WhhB, Wo1, bo1, Wo2, bo2, out);
}

// Round 3
// 452.410 us; speedup vs baseline: 9.3631x; 1.0092x over previous
//
#include <hip/hip_runtime.h>
#include <hip/hip_bf16.h>
#include <math.h>

#define BB 4
#define NN 1024
#define TT 16
#define FIN 32
#define HH 128
#define LH 64
#define MLPH 32

typedef __attribute__((ext_vector_type(8))) short short8;
typedef __attribute__((ext_vector_type(4))) float f32x4;
typedef unsigned short u16;
typedef unsigned int u32;

__device__ __forceinline__ u16 f2b(float f) {
    union { float f; u32 u; } v; v.f = f;
    u32 u = v.u;
    return (u16)((u + 0x7FFFu + ((u >> 16) & 1u)) >> 16);
}
__device__ __forceinline__ float b2f(u16 h) {
    union { u32 u; float f; } v; v.u = ((u32)h) << 16;
    return v.f;
}

// ---------------- precompute: bf16 weight layouts + fused bias ----------------
__global__ void k_pre(const float* __restrict__ W1, const float* __restrict__ W2,
                      const float* __restrict__ W_ih, const float* __restrict__ W_hh,
                      const float* __restrict__ b_ih, const float* __restrict__ b_hh,
                      u16* W1T, u16* W2T, u16* WihB, u16* WhhB, float* bsum) {
    int tid = threadIdx.x;
    for (int i = tid; i < 128 * 32; i += 256) { int c = i >> 5, k = i & 31; W1T[i] = f2b(W1[k * 128 + c]); }
    for (int i = tid; i < 128 * 128; i += 256) { int c = i >> 7, k = i & 127; W2T[i] = f2b(W2[k * 128 + c]); }
    for (int i = tid; i < 256 * 128; i += 256) WihB[i] = f2b(W_ih[i]);
    for (int i = tid; i < 256 * 64; i += 256) WhhB[i] = f2b(W_hh[i]);
    if (tid < 256) bsum[tid] = b_ih[tid] + b_hh[tid];
}

// ---------------- adjacency -> bitmask (1 bit per edge) ----------------
__global__ __launch_bounds__(256) void k_mask(const int* __restrict__ adj, unsigned long long* __restrict__ bm) {
    int gw = (blockIdx.x * 256 + threadIdx.x) >> 6;
    int lane = threadIdx.x & 63;
    for (int u = gw; u < (BB * NN * NN) / 64; u += 1024) {
        unsigned long long m = __ballot(adj[(size_t)u * 64 + lane] > 0);
        if (lane == 0) bm[u] = m;
    }
}

// ---------------- GAT layer-1 projection (MFMA): x -> Wh1^T bf16 + s vectors ----------------
__global__ __launch_bounds__(256) void k_projA(const float* __restrict__ x, const u16* __restrict__ W1T,
                                               const float* __restrict__ a1,
                                               u16* __restrict__ WhT, float* __restrict__ ssrc,
                                               float* __restrict__ sdst) {
    __shared__ float tile[64][132];
    __shared__ float sA[256];
    int bt = blockIdx.x >> 4, i0 = (blockIdx.x & 15) << 6;
    int b = bt >> 4, t = bt & 15;
    int tid = threadIdx.x, w = tid >> 6, l = tid & 63;
    int lr = l & 15, lg = l >> 4;
    sA[tid] = a1[tid];
    int i = i0 + 16 * w + lr;
    const float* xp = x + ((size_t)((b << 10) + i) * TT + t) * FIN + 8 * lg;
    float4 x0 = *(const float4*)xp;
    float4 x1 = *(const float4*)(xp + 4);
    short8 af;
    af[0] = (short)f2b(x0.x); af[1] = (short)f2b(x0.y); af[2] = (short)f2b(x0.z); af[3] = (short)f2b(x0.w);
    af[4] = (short)f2b(x1.x); af[5] = (short)f2b(x1.y); af[6] = (short)f2b(x1.z); af[7] = (short)f2b(x1.w);
    f32x4 zz = {0.f, 0.f, 0.f, 0.f};
#pragma unroll
    for (int tc = 0; tc < 8; ++tc) {
        short8 bf = *(const short8*)(W1T + ((16 * tc + lr) << 5) + 8 * lg);
        f32x4 d = __builtin_amdgcn_mfma_f32_16x16x32_bf16(af, bf, zz, 0, 0, 0);
#pragma unroll
        for (int r = 0; r < 4; ++r) tile[16 * w + 4 * lg + r][16 * tc + lr] = d[r];
    }
    __syncthreads();
    if (tid < 128) {
        int r = tid & 63;
        const float* av = sA + ((tid < 64) ? 0 : 128);
        float s = 0.f;
#pragma unroll 4
        for (int c = 0; c < 128; ++c) s += tile[r][c] * av[c];
        ((tid < 64) ? ssrc : sdst)[(bt << 10) + i0 + r] = s;
    }
    {
        int c = tid & 127, hh2 = tid >> 7;
        u16 tmp[32];
#pragma unroll
        for (int j = 0; j < 32; ++j) tmp[j] = f2b(tile[32 * hh2 + j][c]);
        u16* dst = WhT + (((size_t)(bt << 7) + c) << 10) + i0 + 32 * hh2;
#pragma unroll
        for (int q = 0; q < 4; ++q) *(short8*)(dst + 8 * q) = *(const short8*)(tmp + 8 * q);
    }
}

// ---------------- GAT layer-2 projection (MFMA): h1 bf16 -> Wh2^T bf16 + s vectors ----------------
__global__ __launch_bounds__(256) void k_projB(const u16* __restrict__ h1, const u16* __restrict__ W2T,
                                               const float* __restrict__ a2,
                                               u16* __restrict__ WhT, float* __restrict__ ssrc,
                                               float* __restrict__ sdst) {
    __shared__ float tile[64][132];
    __shared__ float sA[256];
    int bt = blockIdx.x >> 4, i0 = (blockIdx.x & 15) << 6;
    int tid = threadIdx.x, w = tid >> 6, l = tid & 63;
    int lr = l & 15, lg = l >> 4;
    sA[tid] = a2[tid];
    int i = i0 + 16 * w + lr;
    const u16* ap = h1 + (((size_t)(bt << 10) + i) << 7) + 8 * lg;
    f32x4 acc[8];
#pragma unroll
    for (int tc = 0; tc < 8; ++tc) acc[tc] = (f32x4){0.f, 0.f, 0.f, 0.f};
#pragma unroll
    for (int ch = 0; ch < 4; ++ch) {
        short8 af = *(const short8*)(ap + 32 * ch);
#pragma unroll
        for (int tc = 0; tc < 8; ++tc) {
            short8 bf = *(const short8*)(W2T + ((16 * tc + lr) << 7) + 32 * ch + 8 * lg);
            acc[tc] = __builtin_amdgcn_mfma_f32_16x16x32_bf16(af, bf, acc[tc], 0, 0, 0);
        }
    }
#pragma unroll
    for (int tc = 0; tc < 8; ++tc)
#pragma unroll
        for (int r = 0; r < 4; ++r) tile[16 * w + 4 * lg + r][16 * tc + lr] = acc[tc][r];
    __syncthreads();
    if (tid < 128) {
        int r = tid & 63;
        const float* av = sA + ((tid < 64) ? 0 : 128);
        float s = 0.f;
#pragma unroll 4
        for (int c = 0; c < 128; ++c) s += tile[r][c] * av[c];
        ((tid < 64) ? ssrc : sdst)[(bt << 10) + i0 + r] = s;
    }
    {
        int c = tid & 127, hh2 = tid >> 7;
        u16 tmp[32];
#pragma unroll
        for (int j = 0; j < 32; ++j) tmp[j] = f2b(tile[32 * hh2 + j][c]);
        u16* dst = WhT + (((size_t)(bt << 7) + c) << 10) + i0 + 32 * hh2;
#pragma unroll
        for (int q = 0; q < 4; ++q) *(short8*)(dst + 8 * q) = *(const short8*)(tmp + 8 * q);
    }
}

// ---------------- attention (MFMA flash-style): P = max(Ei*Ej, Fi*Fj), masked ----------------
__global__ __launch_bounds__(256, 4) void k_attn(const u16* __restrict__ WhT, const float* __restrict__ ssrc,
                                                 const float* __restrict__ sdst, const u32* __restrict__ bm,
                                                 u16* __restrict__ hout) {
    __shared__ __align__(16) float Ej[1024];
    __shared__ __align__(16) float Fj[1024];
    __shared__ u32 bml[32 * 65];          // [wd][row], stride 65 words: conflict-free
    int bt = blockIdx.x >> 4, i0 = (blockIdx.x & 15) << 6;
    int b = bt >> 4;
    int tid = threadIdx.x, w = tid >> 6, l = tid & 63;
    int lr = l & 15, lg = l >> 4;
    for (int k = tid; k < 1024; k += 256) {
        float sdv = sdst[(bt << 10) + k];
        Ej[k] = __expf(sdv);
        Fj[k] = __expf(0.2f * sdv);
    }
    for (int k = tid; k < 2048; k += 256) {
        int r = k >> 5, wd = k & 31;      // global coalesced in wd
        bml[wd * 65 + r] = bm[(((size_t)(b << 10) + i0 + r) << 5) + wd];
    }
    __syncthreads();
    int i = i0 + 16 * w + lr;
    float si = ssrc[(bt << 10) + i];
    float Ei = __expf(si);
    float Fi = __expf(0.2f * si);
    const u16* wb = WhT + ((size_t)bt << 17) + ((size_t)lr << 10) + 8 * lg;
    f32x4 acc[8];
#pragma unroll
    for (int tc = 0; tc < 8; ++tc) acc[tc] = (f32x4){0.f, 0.f, 0.f, 0.f};
    float psum = 0.f;

    union AFu { u32 u[4]; short8 s; };
    int rowoff = 16 * w + lr;

#define BUILD_AF(JC, AF)                                                         \
    {                                                                            \
        u32 word = bml[(JC) * 65 + rowoff];                                      \
        u32 byt = (word >> (8 * lg)) & 0xFFu;                                    \
        const float* ejp = Ej + 32 * (JC) + 8 * lg;                              \
        const float* fjp = Fj + 32 * (JC) + 8 * lg;                              \
        float4 e0 = *(const float4*)ejp, e1 = *(const float4*)(ejp + 4);         \
        float4 f0 = *(const float4*)fjp, f1 = *(const float4*)(fjp + 4);         \
        float pA[8];                                                             \
        pA[0] = fmaxf(Ei * e0.x, Fi * f0.x);                                     \
        pA[1] = fmaxf(Ei * e0.y, Fi * f0.y);                                     \
        pA[2] = fmaxf(Ei * e0.z, Fi * f0.z);                                     \
        pA[3] = fmaxf(Ei * e0.w, Fi * f0.w);                                     \
        pA[4] = fmaxf(Ei * e1.x, Fi * f1.x);                                     \
        pA[5] = fmaxf(Ei * e1.y, Fi * f1.y);                                     \
        pA[6] = fmaxf(Ei * e1.z, Fi * f1.z);                                     \
        pA[7] = fmaxf(Ei * e1.w, Fi * f1.w);                                     \
        _Pragma("unroll")                                                        \
        for (int q = 0; q < 4; ++q) {                                            \
            u32 m0 = (u32)(-(int)((byt >> (2 * q)) & 1u));                       \
            u32 m1 = (u32)(-(int)((byt >> (2 * q + 1)) & 1u));                   \
            float p0 = __uint_as_float(__float_as_uint(pA[2 * q]) & m0);         \
            float p1 = __uint_as_float(__float_as_uint(pA[2 * q + 1]) & m1);     \
            psum += p0;                                                          \
            psum += p1;                                                          \
            asm("v_cvt_pk_bf16_f32 %0, %1, %2" : "=v"(AF.u[q]) : "v"(p0), "v"(p1)); \
        }                                                                        \
    }

    short8 bA[8], bB[8];
#pragma unroll
    for (int tc = 0; tc < 8; ++tc) bA[tc] = *(const short8*)(wb + ((size_t)tc << 14));

    for (int jc2 = 0; jc2 < 16; ++jc2) {
        int jc = 2 * jc2;
#pragma unroll
        for (int tc = 0; tc < 8; ++tc) bB[tc] = *(const short8*)(wb + ((size_t)tc << 14) + 32 * (jc + 1));
        {
            AFu af;
            BUILD_AF(jc, af)
#pragma unroll
            for (int tc = 0; tc < 8; ++tc) acc[tc] = __builtin_amdgcn_mfma_f32_16x16x32_bf16(af.s, bA[tc], acc[tc], 0, 0, 0);
        }
        if (jc2 < 15) {
#pragma unroll
            for (int tc = 0; tc < 8; ++tc) bA[tc] = *(const short8*)(wb + ((size_t)tc << 14) + 32 * (jc + 2));
        }
        {
            AFu af;
            BUILD_AF(jc + 1, af)
#pragma unroll
            for (int tc = 0; tc < 8; ++tc) acc[tc] = __builtin_amdgcn_mfma_f32_16x16x32_bf16(af.s, bB[tc], acc[tc], 0, 0, 0);
        }
    }
#undef BUILD_AF

    psum += __shfl_xor(psum, 16);
    psum += __shfl_xor(psum, 32);
    float inv[4];
#pragma unroll
    for (int r = 0; r < 4; ++r) inv[r] = 1.f / __shfl(psum, 4 * lg + r);
    size_t obase = ((size_t)((bt << 10) + i0 + 16 * w)) << 7;
#pragma unroll
    for (int tc = 0; tc < 8; ++tc)
#pragma unroll
        for (int r = 0; r < 4; ++r) {
            float v = acc[tc][r] * inv[r];
            v = v > 0.f ? v : (__expf(v) - 1.f);
            v = v > 0.f ? v : (__expf(v) - 1.f);
            hout[obase + ((size_t)(4 * lg + r) << 7) + 16 * tc + lr] = f2b(v);
        }
}

// ---------------- Gx = seq @ W_ih^T + bias (recurrence-free part), bf16 out ----------------
__global__ __launch_bounds__(256) void k_gx(const u16* __restrict__ g, const u16* __restrict__ WihB,
                                            const float* __restrict__ bsum, u16* __restrict__ Gx) {
    int rm0 = blockIdx.x << 6;
    int bt = rm0 >> 10, n0 = rm0 & 1023;
    int b = bt >> 4, t = bt & 15;
    int tid = threadIdx.x, w = tid >> 6, l = tid & 63;
    int lr = l & 15, lg = l >> 4;
    const u16* ap = g + ((size_t)(rm0 + 16 * w + lr) << 7) + 8 * lg;
    f32x4 acc[16];
#pragma unroll
    for (int tc = 0; tc < 16; ++tc) acc[tc] = (f32x4){0.f, 0.f, 0.f, 0.f};
#pragma unroll
    for (int ch = 0; ch < 4; ++ch) {
        short8 af = *(const short8*)(ap + 32 * ch);
#pragma unroll
        for (int tc = 0; tc < 16; ++tc) {
            short8 bf = *(const short8*)(WihB + ((16 * tc + lr) << 7) + 32 * ch + 8 * lg);
            acc[tc] = __builtin_amdgcn_mfma_f32_16x16x32_bf16(af, bf, acc[tc], 0, 0, 0);
        }
    }
    size_t orow = ((size_t)t << 12) + (b << 10) + n0 + 16 * w;
#pragma unroll
    for (int tc = 0; tc < 16; ++tc) {
        float bz = bsum[16 * tc + lr];
#pragma unroll
        for (int r = 0; r < 4; ++r)
            Gx[((orow + 4 * lg + r) << 8) + 16 * tc + lr] = f2b(acc[tc][r] + bz);
    }
}

// ---------------- LSTM recurrence (MFMA, 16 nodes/block, 1 wave) + fused MLP ----------------
__global__ __launch_bounds__(64, 1) void k_lstm(const u16* __restrict__ Gx, const u16* __restrict__ WhhB,
                                                const float* __restrict__ Wo1, const float* __restrict__ bo1,
                                                const float* __restrict__ Wo2, const float* __restrict__ bo2,
                                                float* __restrict__ out) {
    __shared__ u16 hls[16 * 72];
    __shared__ float hf[16 * 65];
    __shared__ float wo1[64 * 32];
    __shared__ float wo2[32];
    int m0 = blockIdx.x << 4;
    int l = threadIdx.x, lr = l & 15, lg = l >> 4;
    for (int k = l; k < 64 * 32; k += 64) wo1[k] = Wo1[k];
    if (l < 32) wo2[l] = Wo2[l];
    for (int k = l; k < 16 * 72; k += 64) hls[k] = 0;
    short8 bh[16][2];
#pragma unroll
    for (int tc = 0; tc < 16; ++tc)
#pragma unroll
        for (int ch = 0; ch < 2; ++ch)
            bh[tc][ch] = *(const short8*)(WhhB + ((16 * tc + lr) << 6) + 32 * ch + 8 * lg);
    float cst[4][4], hreg[4][4];
#pragma unroll
    for (int r = 0; r < 4; ++r)
#pragma unroll
        for (int q = 0; q < 4; ++q) cst[r][q] = 0.f;
    __syncthreads();
    for (int t = 0; t < TT; ++t) {
        f32x4 acc[16];
        size_t gbase = (((size_t)t << 12) + m0) << 8;
#pragma unroll
        for (int tc = 0; tc < 16; ++tc)
#pragma unroll
            for (int r = 0; r < 4; ++r)
                acc[tc][r] = b2f(Gx[gbase + ((size_t)(4 * lg + r) << 8) + 16 * tc + lr]);
#pragma unroll
        for (int ch = 0; ch < 2; ++ch) {
            short8 af = *(const short8*)(hls + lr * 72 + 32 * ch + 8 * lg);
#pragma unroll
            for (int tc = 0; tc < 16; ++tc)
                acc[tc] = __builtin_amdgcn_mfma_f32_16x16x32_bf16(af, bh[tc][ch], acc[tc], 0, 0, 0);
        }
#pragma unroll
        for (int r = 0; r < 4; ++r)
#pragma unroll
            for (int q = 0; q < 4; ++q) {
                float iv = acc[q][r], fv = acc[q + 4][r], gv = acc[q + 8][r], ov = acc[q + 12][r];
                iv = 1.f / (1.f + __expf(-iv));
                fv = 1.f / (1.f + __expf(-fv));
                ov = 1.f / (1.f + __expf(-ov));
                gv = tanhf(gv);
                float cn = fv * cst[r][q] + iv * gv;
                cst[r][q] = cn;
                hreg[r][q] = ov * tanhf(cn);
            }
        __syncthreads();
#pragma unroll
        for (int r = 0; r < 4; ++r)
#pragma unroll
            for (int q = 0; q < 4; ++q)
                hls[(4 * lg + r) * 72 + 16 * q + lr] = f2b(hreg[r][q]);
        __syncthreads();
    }
#pragma unroll
    for (int r = 0; r < 4; ++r)
#pragma unroll
        for (int q = 0; q < 4; ++q)
            hf[(4 * lg + r) * 65 + 16 * q + lr] = hreg[r][q];
    __syncthreads();
    {
        int r = l & 15, p = l >> 4;
        float hid[8];
#pragma unroll
        for (int q = 0; q < 8; ++q) hid[q] = bo1[8 * p + q];
        for (int j = 0; j < 64; ++j) {
            float hv = hf[r * 65 + j];
#pragma unroll
            for (int q = 0; q < 8; ++q) hid[q] += hv * wo1[j * 32 + 8 * p + q];
        }
        float po = 0.f;
#pragma unroll
        for (int q = 0; q < 8; ++q) po += fmaxf(hid[q], 0.f) * wo2[8 * p + q];
        po += __shfl_xor(po, 16);
        po += __shfl_xor(po, 32);
        if (p == 0) out[m0 + r] = po + bo2[0];
    }
}

extern "C" void kernel_launch(void* const* d_in, const int* in_sizes, int n_in,
                              void* d_out, int out_size, void* d_ws, size_t ws_size,
                              hipStream_t stream) {
    const float* x    = (const float*)d_in[0];
    const int*   adj  = (const int*)d_in[1];
    const float* W1   = (const float*)d_in[2];
    const float* a1   = (const float*)d_in[3];
    const float* W2   = (const float*)d_in[4];
    const float* a2   = (const float*)d_in[5];
    const float* W_ih = (const float*)d_in[6];
    const float* W_hh = (const float*)d_in[7];
    const float* b_ih = (const float*)d_in[8];
    const float* b_hh = (const float*)d_in[9];
    const float* Wo1  = (const float*)d_in[10];
    const float* bo1  = (const float*)d_in[11];
    const float* Wo2  = (const float*)d_in[12];
    const float* bo2  = (const float*)d_in[13];
    float* out = (float*)d_out;

    char* w = (char*)d_ws;
    const size_t SLOT = (size_t)8388608 * sizeof(u16);   // 16.78 MB
    u16* A  = (u16*)w;
    u16* Bf = (u16*)(w + SLOT);
    u16* C  = (u16*)(w + 2 * SLOT);
    char* sm = w + 3 * SLOT;
    float* s1s = (float*)sm;
    float* s1d = s1s + 65536;
    float* s2s = s1d + 65536;
    float* s2d = s2s + 65536;
    u32* BM  = (u32*)(s2d + 65536);      // 131072 words (512 KB)
    u16* W1T = (u16*)(BM + 131072);      // 4096
    u16* W2T = W1T + 4096;               // 16384
    u16* WihB = W2T + 16384;             // 32768
    u16* WhhB = WihB + 32768;            // 16384
    float* BS = (float*)(WhhB + 16384);  // 256
    u16* Gx = Bf;                        // spans Bf..C (33.55 MB), used after both are dead

    k_pre<<<1, 256, 0, stream>>>(W1, W2, W_ih, W_hh, b_ih, b_hh, W1T, W2T, WihB, WhhB, BS);
    k_mask<<<256, 256, 0, stream>>>(adj, (unsigned long long*)BM);
    k_projA<<<1024, 256, 0, stream>>>(x, W1T, a1, A, s1s, s1d);
    k_attn<<<1024, 256, 0, stream>>>(A, s1s, s1d, BM, Bf);
    k_projB<<<1024, 256, 0, stream>>>(Bf, W2T, a2, C, s2s, s2d);
    k_attn<<<1024, 256, 0, stream>>>(C, s2s, s2d, BM, A);
    k_gx<<<1024, 256, 0, stream>>>(A, WihB, BS, Gx);
    k_lstm<<<256, 64, 0, stream>>>(Gx, WhhB, Wo1, bo1, Wo2, bo2, out);
}

// Round 4
// 285.789 us; speedup vs baseline: 14.8220x; 1.5830x over previous
//
#include <hip/hip_runtime.h>
#include <hip/hip_bf16.h>
#include <math.h>

#define BB 4
#define NN 1024
#define TT 16
#define FIN 32
#define HH 128
#define LH 64
#define MLPH 32

typedef __attribute__((ext_vector_type(8))) short short8;
typedef __attribute__((ext_vector_type(4))) float f32x4;
typedef unsigned short u16;
typedef unsigned int u32;

union AFu { u32 u[4]; short8 s; };

__device__ __forceinline__ u16 f2b(float f) {
    union { float f; u32 u; } v; v.f = f;
    u32 u = v.u;
    return (u16)((u + 0x7FFFu + ((u >> 16) & 1u)) >> 16);
}
__device__ __forceinline__ float b2f(u16 h) {
    union { u32 u; float f; } v; v.u = ((u32)h) << 16;
    return v.f;
}
__device__ __forceinline__ void gload_lds16(const void* g, void* l) {
    __builtin_amdgcn_global_load_lds((const __attribute__((address_space(1))) unsigned int*)g,
                                     (__attribute__((address_space(3))) unsigned int*)l, 16, 0, 0);
}

// ---------------- precompute: bf16 weight layouts + fused bias ----------------
__global__ void k_pre(const float* __restrict__ W1, const float* __restrict__ W2,
                      const float* __restrict__ W_ih, const float* __restrict__ W_hh,
                      const float* __restrict__ b_ih, const float* __restrict__ b_hh,
                      u16* W1T, u16* W2T, u16* WihB, u16* WhhB, float* bsum) {
    int tid = threadIdx.x;
    for (int i = tid; i < 128 * 32; i += 256) { int c = i >> 5, k = i & 31; W1T[i] = f2b(W1[k * 128 + c]); }
    for (int i = tid; i < 128 * 128; i += 256) { int c = i >> 7, k = i & 127; W2T[i] = f2b(W2[k * 128 + c]); }
    for (int i = tid; i < 256 * 128; i += 256) WihB[i] = f2b(W_ih[i]);
    for (int i = tid; i < 256 * 64; i += 256) WhhB[i] = f2b(W_hh[i]);
    if (tid < 256) bsum[tid] = b_ih[tid] + b_hh[tid];
}

// ---------------- adjacency -> bitmask (1 bit per edge) ----------------
__global__ __launch_bounds__(256) void k_mask(const int* __restrict__ adj, unsigned long long* __restrict__ bm) {
    int gw = (blockIdx.x * 256 + threadIdx.x) >> 6;
    int lane = threadIdx.x & 63;
    for (int u = gw; u < (BB * NN * NN) / 64; u += 1024) {
        unsigned long long m = __ballot(adj[(size_t)u * 64 + lane] > 0);
        if (lane == 0) bm[u] = m;
    }
}

// ---------------- GAT layer-1 projection (MFMA): x -> Wh1^T bf16 + s vectors ----------------
__global__ __launch_bounds__(256) void k_projA(const float* __restrict__ x, const u16* __restrict__ W1T,
                                               const float* __restrict__ a1,
                                               u16* __restrict__ WhT, float* __restrict__ ssrc,
                                               float* __restrict__ sdst) {
    __shared__ float tile[64][132];
    __shared__ float sA[256];
    int bt = blockIdx.x >> 4, i0 = (blockIdx.x & 15) << 6;
    int b = bt >> 4, t = bt & 15;
    int tid = threadIdx.x, w = tid >> 6, l = tid & 63;
    int lr = l & 15, lg = l >> 4;
    sA[tid] = a1[tid];
    int i = i0 + 16 * w + lr;
    const float* xp = x + ((size_t)((b << 10) + i) * TT + t) * FIN + 8 * lg;
    float4 x0 = *(const float4*)xp;
    float4 x1 = *(const float4*)(xp + 4);
    short8 af;
    af[0] = (short)f2b(x0.x); af[1] = (short)f2b(x0.y); af[2] = (short)f2b(x0.z); af[3] = (short)f2b(x0.w);
    af[4] = (short)f2b(x1.x); af[5] = (short)f2b(x1.y); af[6] = (short)f2b(x1.z); af[7] = (short)f2b(x1.w);
    f32x4 zz = {0.f, 0.f, 0.f, 0.f};
#pragma unroll
    for (int tc = 0; tc < 8; ++tc) {
        short8 bf = *(const short8*)(W1T + ((16 * tc + lr) << 5) + 8 * lg);
        f32x4 d = __builtin_amdgcn_mfma_f32_16x16x32_bf16(af, bf, zz, 0, 0, 0);
#pragma unroll
        for (int r = 0; r < 4; ++r) tile[16 * w + 4 * lg + r][16 * tc + lr] = d[r];
    }
    __syncthreads();
    if (tid < 128) {
        int r = tid & 63;
        const float* av = sA + ((tid < 64) ? 0 : 128);
        float s = 0.f;
#pragma unroll 4
        for (int c = 0; c < 128; ++c) s += tile[r][c] * av[c];
        ((tid < 64) ? ssrc : sdst)[(bt << 10) + i0 + r] = s;
    }
    {
        int c = tid & 127, hh2 = tid >> 7;
        u16 tmp[32];
#pragma unroll
        for (int j = 0; j < 32; ++j) tmp[j] = f2b(tile[32 * hh2 + j][c]);
        u16* dst = WhT + (((size_t)(bt << 7) + c) << 10) + i0 + 32 * hh2;
#pragma unroll
        for (int q = 0; q < 4; ++q) *(short8*)(dst + 8 * q) = *(const short8*)(tmp + 8 * q);
    }
}

// ---------------- GAT layer-2 projection (MFMA): h1 bf16 -> Wh2^T bf16 + s vectors ----------------
__global__ __launch_bounds__(256) void k_projB(const u16* __restrict__ h1, const u16* __restrict__ W2T,
                                               const float* __restrict__ a2,
                                               u16* __restrict__ WhT, float* __restrict__ ssrc,
                                               float* __restrict__ sdst) {
    __shared__ float tile[64][132];
    __shared__ float sA[256];
    int bt = blockIdx.x >> 4, i0 = (blockIdx.x & 15) << 6;
    int tid = threadIdx.x, w = tid >> 6, l = tid & 63;
    int lr = l & 15, lg = l >> 4;
    sA[tid] = a2[tid];
    int i = i0 + 16 * w + lr;
    const u16* ap = h1 + (((size_t)(bt << 10) + i) << 7) + 8 * lg;
    f32x4 acc[8];
#pragma unroll
    for (int tc = 0; tc < 8; ++tc) acc[tc] = (f32x4){0.f, 0.f, 0.f, 0.f};
#pragma unroll
    for (int ch = 0; ch < 4; ++ch) {
        short8 af = *(const short8*)(ap + 32 * ch);
#pragma unroll
        for (int tc = 0; tc < 8; ++tc) {
            short8 bf = *(const short8*)(W2T + ((16 * tc + lr) << 7) + 32 * ch + 8 * lg);
            acc[tc] = __builtin_amdgcn_mfma_f32_16x16x32_bf16(af, bf, acc[tc], 0, 0, 0);
        }
    }
#pragma unroll
    for (int tc = 0; tc < 8; ++tc)
#pragma unroll
        for (int r = 0; r < 4; ++r) tile[16 * w + 4 * lg + r][16 * tc + lr] = acc[tc][r];
    __syncthreads();
    if (tid < 128) {
        int r = tid & 63;
        const float* av = sA + ((tid < 64) ? 0 : 128);
        float s = 0.f;
#pragma unroll 4
        for (int c = 0; c < 128; ++c) s += tile[r][c] * av[c];
        ((tid < 64) ? ssrc : sdst)[(bt << 10) + i0 + r] = s;
    }
    {
        int c = tid & 127, hh2 = tid >> 7;
        u16 tmp[32];
#pragma unroll
        for (int j = 0; j < 32; ++j) tmp[j] = f2b(tile[32 * hh2 + j][c]);
        u16* dst = WhT + (((size_t)(bt << 7) + c) << 10) + i0 + 32 * hh2;
#pragma unroll
        for (int q = 0; q < 4; ++q) *(short8*)(dst + 8 * q) = *(const short8*)(tmp + 8 * q);
    }
}

// ---------------- attention: LDS-staged B double-buffer, M=32/wave ----------------
__global__ __launch_bounds__(256, 2) void k_attn(const u16* __restrict__ WhT, const float* __restrict__ ssrc,
                                                 const float* __restrict__ sdst, const u32* __restrict__ bm,
                                                 u16* __restrict__ hout) {
    __shared__ __align__(16) u16 Bbuf[2][8192];     // 2 x 16KB: chunk = 2 jc (64 j-rows x 128 cols)
    __shared__ __align__(16) float Ej[1024];
    __shared__ __align__(16) float Fj[1024];
    __shared__ u32 bml[32 * 132];                   // [wd][blockrow], pad 132
    int bt = blockIdx.x >> 3, i0b = (blockIdx.x & 7) << 7;
    int b = bt >> 4;
    int tid = threadIdx.x, wv = tid >> 6, l = tid & 63;
    int lr = l & 15, lg = l >> 4;

    for (int k = tid; k < 1024; k += 256) {
        float sdv = sdst[(bt << 10) + k];
        Ej[k] = __expf(sdv);
        Fj[k] = __expf(0.2f * sdv);
    }
    for (int k = tid; k < 4096; k += 256) {
        int r = k >> 5, wd = k & 31;
        bml[wd * 132 + r] = bm[(((size_t)(b << 10) + i0b + r) << 5) + wd];
    }
    const u16* wbase = WhT + ((size_t)bt << 17);
    {   // stage chunk 0
        int u0 = wv << 2;
#pragma unroll
        for (int p = 0; p < 4; ++p) {
            int u = u0 + p;
            const u16* gs = wbase + ((((u & 7) << 4) + lr) << 10) + ((u >> 3) << 5) + 8 * lg;
            gload_lds16(gs, Bbuf[0] + u * 512);
        }
    }
    int rb = i0b + (wv << 5);
    float si0 = ssrc[(bt << 10) + rb + lr];
    float si1 = ssrc[(bt << 10) + rb + 16 + lr];
    float Ei0 = __expf(si0), Fi0 = __expf(0.2f * si0);
    float Ei1 = __expf(si1), Fi1 = __expf(0.2f * si1);
    f32x4 acc[2][8];
#pragma unroll
    for (int rt = 0; rt < 2; ++rt)
#pragma unroll
        for (int tc = 0; tc < 8; ++tc) acc[rt][tc] = (f32x4){0.f, 0.f, 0.f, 0.f};
    float ps0 = 0.f, ps1 = 0.f;
    int rl0 = (wv << 5) + lr;
    __syncthreads();

    for (int c = 0; c < 16; ++c) {
        int cur = c & 1;
        if (c < 15) {
            int u0 = wv << 2;
#pragma unroll
            for (int p = 0; p < 4; ++p) {
                int u = u0 + p;
                const u16* gs = wbase + ((((u & 7) << 4) + lr) << 10) + ((2 * (c + 1) + (u >> 3)) << 5) + 8 * lg;
                gload_lds16(gs, Bbuf[cur ^ 1] + u * 512);
            }
        }
#pragma unroll
        for (int jcl = 0; jcl < 2; ++jcl) {
            int jc = 2 * c + jcl;
            short8 bfr[8];
#pragma unroll
            for (int tc = 0; tc < 8; ++tc)
                bfr[tc] = *(const short8*)(Bbuf[cur] + ((((jcl << 3) + tc) << 6) + l) * 8);
            const float* ejp = Ej + (jc << 5) + (lg << 3);
            const float* fjp = Fj + (jc << 5) + (lg << 3);
            float4 e0 = *(const float4*)ejp, e1 = *(const float4*)(ejp + 4);
            float4 f0 = *(const float4*)fjp, f1 = *(const float4*)(fjp + 4);
            u32 w0 = bml[jc * 132 + rl0];
            u32 w1 = bml[jc * 132 + rl0 + 16];
            AFu af0, af1;
            {
                u32 byt = (w0 >> (lg << 3)) & 0xFFu;
                float pA[8] = {fmaxf(Ei0 * e0.x, Fi0 * f0.x), fmaxf(Ei0 * e0.y, Fi0 * f0.y),
                               fmaxf(Ei0 * e0.z, Fi0 * f0.z), fmaxf(Ei0 * e0.w, Fi0 * f0.w),
                               fmaxf(Ei0 * e1.x, Fi0 * f1.x), fmaxf(Ei0 * e1.y, Fi0 * f1.y),
                               fmaxf(Ei0 * e1.z, Fi0 * f1.z), fmaxf(Ei0 * e1.w, Fi0 * f1.w)};
#pragma unroll
                for (int q = 0; q < 4; ++q) {
                    u32 m0 = (u32)(-(int)((byt >> (2 * q)) & 1u));
                    u32 m1 = (u32)(-(int)((byt >> (2 * q + 1)) & 1u));
                    float p0 = __uint_as_float(__float_as_uint(pA[2 * q]) & m0);
                    float p1 = __uint_as_float(__float_as_uint(pA[2 * q + 1]) & m1);
                    ps0 += p0; ps0 += p1;
                    asm("v_cvt_pk_bf16_f32 %0, %1, %2" : "=v"(af0.u[q]) : "v"(p0), "v"(p1));
                }
            }
            {
                u32 byt = (w1 >> (lg << 3)) & 0xFFu;
                float pA[8] = {fmaxf(Ei1 * e0.x, Fi1 * f0.x), fmaxf(Ei1 * e0.y, Fi1 * f0.y),
                               fmaxf(Ei1 * e0.z, Fi1 * f0.z), fmaxf(Ei1 * e0.w, Fi1 * f0.w),
                               fmaxf(Ei1 * e1.x, Fi1 * f1.x), fmaxf(Ei1 * e1.y, Fi1 * f1.y),
                               fmaxf(Ei1 * e1.z, Fi1 * f1.z), fmaxf(Ei1 * e1.w, Fi1 * f1.w)};
#pragma unroll
                for (int q = 0; q < 4; ++q) {
                    u32 m0 = (u32)(-(int)((byt >> (2 * q)) & 1u));
                    u32 m1 = (u32)(-(int)((byt >> (2 * q + 1)) & 1u));
                    float p0 = __uint_as_float(__float_as_uint(pA[2 * q]) & m0);
                    float p1 = __uint_as_float(__float_as_uint(pA[2 * q + 1]) & m1);
                    ps1 += p0; ps1 += p1;
                    asm("v_cvt_pk_bf16_f32 %0, %1, %2" : "=v"(af1.u[q]) : "v"(p0), "v"(p1));
                }
            }
#pragma unroll
            for (int tc = 0; tc < 8; ++tc) {
                acc[0][tc] = __builtin_amdgcn_mfma_f32_16x16x32_bf16(af0.s, bfr[tc], acc[0][tc], 0, 0, 0);
                acc[1][tc] = __builtin_amdgcn_mfma_f32_16x16x32_bf16(af1.s, bfr[tc], acc[1][tc], 0, 0, 0);
            }
        }
        __syncthreads();   // drains vmcnt (prefetch) + orders buffer reuse
    }

    ps0 += __shfl_xor(ps0, 16); ps0 += __shfl_xor(ps0, 32);
    ps1 += __shfl_xor(ps1, 16); ps1 += __shfl_xor(ps1, 32);
#pragma unroll
    for (int rt = 0; rt < 2; ++rt) {
        float inv[4];
#pragma unroll
        for (int r = 0; r < 4; ++r) inv[r] = 1.f / __shfl(rt ? ps1 : ps0, (lg << 2) + r);
        size_t obase = ((size_t)((bt << 10) + rb + (rt << 4))) << 7;
#pragma unroll
        for (int tc = 0; tc < 8; ++tc)
#pragma unroll
            for (int r = 0; r < 4; ++r) {
                float v = acc[rt][tc][r] * inv[r];
                v = v > 0.f ? v : (__expf(v) - 1.f);
                v = v > 0.f ? v : (__expf(v) - 1.f);
                hout[obase + ((size_t)((lg << 2) + r) << 7) + (tc << 4) + lr] = f2b(v);
            }
    }
}

// ---------------- Gx = seq @ W_ih^T + bias, written in MFMA-fragment order ----------------
__global__ __launch_bounds__(256) void k_gx(const u16* __restrict__ g, const u16* __restrict__ WihB,
                                            const float* __restrict__ bsum, u16* __restrict__ Gx) {
    int rm0 = blockIdx.x << 6;
    int bt = rm0 >> 10, n0 = rm0 & 1023;
    int b = bt >> 4, t = bt & 15;
    int tid = threadIdx.x, w = tid >> 6, l = tid & 63;
    int lr = l & 15, lg = l >> 4;
    const u16* ap = g + ((size_t)(rm0 + 16 * w + lr) << 7) + 8 * lg;
    f32x4 acc[16];
#pragma unroll
    for (int tc = 0; tc < 16; ++tc) acc[tc] = (f32x4){0.f, 0.f, 0.f, 0.f};
#pragma unroll
    for (int ch = 0; ch < 4; ++ch) {
        short8 af = *(const short8*)(ap + 32 * ch);
#pragma unroll
        for (int tc = 0; tc < 16; ++tc) {
            short8 bf = *(const short8*)(WihB + ((16 * tc + lr) << 7) + 32 * ch + 8 * lg);
            acc[tc] = __builtin_amdgcn_mfma_f32_16x16x32_bf16(af, bf, acc[tc], 0, 0, 0);
        }
    }
    // fragment layout: [t][grp][q(=tc pair)][lane] of 8 u16
    int grp = (b << 6) + (n0 >> 4) + w;
    u16* gdst = Gx + (size_t)t * 1048576 + (size_t)grp * 4096 + l * 8;
#pragma unroll
    for (int q = 0; q < 8; ++q) {
        short8 v;
#pragma unroll
        for (int r = 0; r < 4; ++r) {
            v[r]     = (short)f2b(acc[2 * q][r]     + bsum[((2 * q) << 4) + lr]);
            v[4 + r] = (short)f2b(acc[2 * q + 1][r] + bsum[((2 * q + 1) << 4) + lr]);
        }
        *(short8*)(gdst + q * 512) = v;
    }
}

// ---------------- LSTM recurrence (MFMA, 16 nodes/block) + fused MLP ----------------
__global__ __launch_bounds__(64, 1) void k_lstm(const u16* __restrict__ Gx, const u16* __restrict__ WhhB,
                                                const float* __restrict__ Wo1, const float* __restrict__ bo1,
                                                const float* __restrict__ Wo2, const float* __restrict__ bo2,
                                                float* __restrict__ out) {
    __shared__ u16 hls[16 * 72];
    __shared__ float hf[16 * 65];
    __shared__ float wo1[64 * 32];
    __shared__ float wo2[32];
    int grp = blockIdx.x;
    int m0 = grp << 4;
    int l = threadIdx.x, lr = l & 15, lg = l >> 4;
    for (int k = l; k < 64 * 32; k += 64) wo1[k] = Wo1[k];
    if (l < 32) wo2[l] = Wo2[l];
    for (int k = l; k < 16 * 72; k += 64) hls[k] = 0;
    short8 bh[16][2];
#pragma unroll
    for (int tc = 0; tc < 16; ++tc)
#pragma unroll
        for (int ch = 0; ch < 2; ++ch)
            bh[tc][ch] = *(const short8*)(WhhB + ((16 * tc + lr) << 6) + 32 * ch + 8 * lg);
    float cst[4][4], hreg[4][4];
#pragma unroll
    for (int r = 0; r < 4; ++r)
#pragma unroll
        for (int q = 0; q < 4; ++q) cst[r][q] = 0.f;
    const u16* gp = Gx + ((size_t)grp << 12) + l * 8;
    short8 gx0[8], gx1[8];
#pragma unroll
    for (int q = 0; q < 8; ++q) gx0[q] = *(const short8*)(gp + q * 512);
    __syncthreads();
#pragma unroll
    for (int t = 0; t < TT; ++t) {
        if (t < 15) {     // prefetch next step's Gx fragments
#pragma unroll
            for (int q = 0; q < 8; ++q) {
                short8 v = *(const short8*)(gp + (size_t)(t + 1) * 1048576 + q * 512);
                if (t & 1) gx0[q] = v; else gx1[q] = v;
            }
        }
        f32x4 acc[16];
#pragma unroll
        for (int q = 0; q < 8; ++q) {
            short8 v = (t & 1) ? gx1[q] : gx0[q];
#pragma unroll
            for (int r = 0; r < 4; ++r) {
                acc[2 * q][r]     = b2f((u16)v[r]);
                acc[2 * q + 1][r] = b2f((u16)v[4 + r]);
            }
        }
#pragma unroll
        for (int ch = 0; ch < 2; ++ch) {
            short8 af = *(const short8*)(hls + lr * 72 + 32 * ch + 8 * lg);
#pragma unroll
            for (int tc = 0; tc < 16; ++tc)
                acc[tc] = __builtin_amdgcn_mfma_f32_16x16x32_bf16(af, bh[tc][ch], acc[tc], 0, 0, 0);
        }
#pragma unroll
        for (int r = 0; r < 4; ++r)
#pragma unroll
            for (int q = 0; q < 4; ++q) {
                float iv = acc[q][r], fv = acc[q + 4][r], gv = acc[q + 8][r], ov = acc[q + 12][r];
                iv = 1.f / (1.f + __expf(-iv));
                fv = 1.f / (1.f + __expf(-fv));
                ov = 1.f / (1.f + __expf(-ov));
                gv = tanhf(gv);
                float cn = fv * cst[r][q] + iv * gv;
                cst[r][q] = cn;
                hreg[r][q] = ov * tanhf(cn);
            }
        __syncthreads();
#pragma unroll
        for (int r = 0; r < 4; ++r)
#pragma unroll
            for (int q = 0; q < 4; ++q)
                hls[(4 * lg + r) * 72 + 16 * q + lr] = f2b(hreg[r][q]);
        __syncthreads();
    }
#pragma unroll
    for (int r = 0; r < 4; ++r)
#pragma unroll
        for (int q = 0; q < 4; ++q)
            hf[(4 * lg + r) * 65 + 16 * q + lr] = hreg[r][q];
    __syncthreads();
    {
        int r = l & 15, p = l >> 4;
        float hid[8];
#pragma unroll
        for (int q = 0; q < 8; ++q) hid[q] = bo1[8 * p + q];
        for (int j = 0; j < 64; ++j) {
            float hv = hf[r * 65 + j];
#pragma unroll
            for (int q = 0; q < 8; ++q) hid[q] += hv * wo1[j * 32 + 8 * p + q];
        }
        float po = 0.f;
#pragma unroll
        for (int q = 0; q < 8; ++q) po += fmaxf(hid[q], 0.f) * wo2[8 * p + q];
        po += __shfl_xor(po, 16);
        po += __shfl_xor(po, 32);
        if (p == 0) out[m0 + r] = po + bo2[0];
    }
}

extern "C" void kernel_launch(void* const* d_in, const int* in_sizes, int n_in,
                              void* d_out, int out_size, void* d_ws, size_t ws_size,
                              hipStream_t stream) {
    const float* x    = (const float*)d_in[0];
    const int*   adj  = (const int*)d_in[1];
    const float* W1   = (const float*)d_in[2];
    const float* a1   = (const float*)d_in[3];
    const float* W2   = (const float*)d_in[4];
    const float* a2   = (const float*)d_in[5];
    const float* W_ih = (const float*)d_in[6];
    const float* W_hh = (const float*)d_in[7];
    const float* b_ih = (const float*)d_in[8];
    const float* b_hh = (const float*)d_in[9];
    const float* Wo1  = (const float*)d_in[10];
    const float* bo1  = (const float*)d_in[11];
    const float* Wo2  = (const float*)d_in[12];
    const float* bo2  = (const float*)d_in[13];
    float* out = (float*)d_out;

    char* w = (char*)d_ws;
    const size_t SLOT = (size_t)8388608 * sizeof(u16);   // 16.78 MB
    u16* A  = (u16*)w;
    u16* Bf = (u16*)(w + SLOT);
    u16* C  = (u16*)(w + 2 * SLOT);
    char* sm = w + 3 * SLOT;
    float* s1s = (float*)sm;
    float* s1d = s1s + 65536;
    float* s2s = s1d + 65536;
    float* s2d = s2s + 65536;
    u32* BM  = (u32*)(s2d + 65536);      // 131072 words (512 KB)
    u16* W1T = (u16*)(BM + 131072);      // 4096
    u16* W2T = W1T + 4096;               // 16384
    u16* WihB = W2T + 16384;             // 32768
    u16* WhhB = WihB + 32768;            // 16384
    float* BS = (float*)(WhhB + 16384);  // 256
    u16* Gx = Bf;                        // spans Bf..C (33.55 MB), used after both are dead

    k_pre<<<1, 256, 0, stream>>>(W1, W2, W_ih, W_hh, b_ih, b_hh, W1T, W2T, WihB, WhhB, BS);
    k_mask<<<256, 256, 0, stream>>>(adj, (unsigned long long*)BM);
    k_projA<<<1024, 256, 0, stream>>>(x, W1T, a1, A, s1s, s1d);
    k_attn<<<512, 256, 0, stream>>>(A, s1s, s1d, BM, Bf);
    k_projB<<<1024, 256, 0, stream>>>(Bf, W2T, a2, C, s2s, s2d);
    k_attn<<<512, 256, 0, stream>>>(C, s2s, s2d, BM, A);
    k_gx<<<1024, 256, 0, stream>>>(A, WihB, BS, Gx);
    k_lstm<<<256, 64, 0, stream>>>(Gx, WhhB, Wo1, bo1, Wo2, bo2, out);
}

// Round 5
// 248.194 us; speedup vs baseline: 17.0672x; 1.1515x over previous
//
#include <hip/hip_runtime.h>
#include <hip/hip_bf16.h>
#include <math.h>

#define BB 4
#define NN 1024
#define TT 16
#define FIN 32
#define HH 128
#define LH 64
#define MLPH 32

typedef __attribute__((ext_vector_type(8))) short short8;
typedef __attribute__((ext_vector_type(4))) float f32x4;
typedef unsigned short u16;
typedef unsigned int u32;

union AFu { u32 u[4]; short8 s; };

__device__ __forceinline__ u16 f2b(float f) {
    union { float f; u32 u; } v; v.f = f;
    u32 u = v.u;
    return (u16)((u + 0x7FFFu + ((u >> 16) & 1u)) >> 16);
}
__device__ __forceinline__ float b2f(u16 h) {
    union { u32 u; float f; } v; v.u = ((u32)h) << 16;
    return v.f;
}
__device__ __forceinline__ float frcp(float x) {
    float r; asm("v_rcp_f32 %0, %1" : "=v"(r) : "v"(x)); return r;
}
__device__ __forceinline__ float fsig(float x) {          // 1/(1+e^-x)
    return frcp(1.f + __expf(-x));
}
__device__ __forceinline__ float ftanh(float x) {         // 2*sig(2x)-1
    return __builtin_fmaf(2.f, frcp(1.f + __expf(-2.f * x)), -1.f);
}
__device__ __forceinline__ void gload_lds16(const void* g, void* l) {
    __builtin_amdgcn_global_load_lds((const __attribute__((address_space(1))) unsigned int*)g,
                                     (__attribute__((address_space(3))) unsigned int*)l, 16, 0, 0);
}

// ---------------- precompute: bf16 weight layouts + fused bias ----------------
__global__ void k_pre(const float* __restrict__ W1, const float* __restrict__ W2,
                      const float* __restrict__ W_ih, const float* __restrict__ W_hh,
                      const float* __restrict__ b_ih, const float* __restrict__ b_hh,
                      u16* W1T, u16* W2T, u16* WihB, u16* WhhB, float* bsum) {
    int tid = threadIdx.x;
    for (int i = tid; i < 128 * 32; i += 256) { int c = i >> 5, k = i & 31; W1T[i] = f2b(W1[k * 128 + c]); }
    for (int i = tid; i < 128 * 128; i += 256) { int c = i >> 7, k = i & 127; W2T[i] = f2b(W2[k * 128 + c]); }
    for (int i = tid; i < 256 * 128; i += 256) WihB[i] = f2b(W_ih[i]);
    for (int i = tid; i < 256 * 64; i += 256) WhhB[i] = f2b(W_hh[i]);
    if (tid < 256) bsum[tid] = b_ih[tid] + b_hh[tid];
}

// ---------------- adjacency -> bitmask (1 bit per edge) ----------------
__global__ __launch_bounds__(256) void k_mask(const int* __restrict__ adj, unsigned long long* __restrict__ bm) {
    int gw = (blockIdx.x * 256 + threadIdx.x) >> 6;
    int lane = threadIdx.x & 63;
    for (int u = gw; u < (BB * NN * NN) / 64; u += 1024) {
        unsigned long long m = __ballot(adj[(size_t)u * 64 + lane] > 0);
        if (lane == 0) bm[u] = m;
    }
}

// ---------------- GAT layer-1 projection (MFMA): x -> Wh1^T bf16 + s vectors ----------------
__global__ __launch_bounds__(256) void k_projA(const float* __restrict__ x, const u16* __restrict__ W1T,
                                               const float* __restrict__ a1,
                                               u16* __restrict__ WhT, float* __restrict__ ssrc,
                                               float* __restrict__ sdst) {
    __shared__ float tile[64][132];
    __shared__ float sA[256];
    int bt = blockIdx.x >> 4, i0 = (blockIdx.x & 15) << 6;
    int b = bt >> 4, t = bt & 15;
    int tid = threadIdx.x, w = tid >> 6, l = tid & 63;
    int lr = l & 15, lg = l >> 4;
    sA[tid] = a1[tid];
    int i = i0 + 16 * w + lr;
    const float* xp = x + ((size_t)((b << 10) + i) * TT + t) * FIN + 8 * lg;
    float4 x0 = *(const float4*)xp;
    float4 x1 = *(const float4*)(xp + 4);
    short8 af;
    af[0] = (short)f2b(x0.x); af[1] = (short)f2b(x0.y); af[2] = (short)f2b(x0.z); af[3] = (short)f2b(x0.w);
    af[4] = (short)f2b(x1.x); af[5] = (short)f2b(x1.y); af[6] = (short)f2b(x1.z); af[7] = (short)f2b(x1.w);
    f32x4 zz = {0.f, 0.f, 0.f, 0.f};
#pragma unroll
    for (int tc = 0; tc < 8; ++tc) {
        short8 bf = *(const short8*)(W1T + ((16 * tc + lr) << 5) + 8 * lg);
        f32x4 d = __builtin_amdgcn_mfma_f32_16x16x32_bf16(af, bf, zz, 0, 0, 0);
#pragma unroll
        for (int r = 0; r < 4; ++r) tile[16 * w + 4 * lg + r][16 * tc + lr] = d[r];
    }
    __syncthreads();
    if (tid < 128) {
        int r = tid & 63;
        const float* av = sA + ((tid < 64) ? 0 : 128);
        float s = 0.f;
#pragma unroll 4
        for (int c = 0; c < 128; ++c) s += tile[r][c] * av[c];
        ((tid < 64) ? ssrc : sdst)[(bt << 10) + i0 + r] = s;
    }
    {
        int c = tid & 127, hh2 = tid >> 7;
        u16 tmp[32];
#pragma unroll
        for (int j = 0; j < 32; ++j) tmp[j] = f2b(tile[32 * hh2 + j][c]);
        u16* dst = WhT + (((size_t)(bt << 7) + c) << 10) + i0 + 32 * hh2;
#pragma unroll
        for (int q = 0; q < 4; ++q) *(short8*)(dst + 8 * q) = *(const short8*)(tmp + 8 * q);
    }
}

// ---------------- GAT layer-2 projection (MFMA): h1 bf16 -> Wh2^T bf16 + s vectors ----------------
__global__ __launch_bounds__(256) void k_projB(const u16* __restrict__ h1, const u16* __restrict__ W2T,
                                               const float* __restrict__ a2,
                                               u16* __restrict__ WhT, float* __restrict__ ssrc,
                                               float* __restrict__ sdst) {
    __shared__ float tile[64][132];
    __shared__ float sA[256];
    int bt = blockIdx.x >> 4, i0 = (blockIdx.x & 15) << 6;
    int tid = threadIdx.x, w = tid >> 6, l = tid & 63;
    int lr = l & 15, lg = l >> 4;
    sA[tid] = a2[tid];
    int i = i0 + 16 * w + lr;
    const u16* ap = h1 + (((size_t)(bt << 10) + i) << 7) + 8 * lg;
    f32x4 acc[8];
#pragma unroll
    for (int tc = 0; tc < 8; ++tc) acc[tc] = (f32x4){0.f, 0.f, 0.f, 0.f};
#pragma unroll
    for (int ch = 0; ch < 4; ++ch) {
        short8 af = *(const short8*)(ap + 32 * ch);
#pragma unroll
        for (int tc = 0; tc < 8; ++tc) {
            short8 bf = *(const short8*)(W2T + ((16 * tc + lr) << 7) + 32 * ch + 8 * lg);
            acc[tc] = __builtin_amdgcn_mfma_f32_16x16x32_bf16(af, bf, acc[tc], 0, 0, 0);
        }
    }
#pragma unroll
    for (int tc = 0; tc < 8; ++tc)
#pragma unroll
        for (int r = 0; r < 4; ++r) tile[16 * w + 4 * lg + r][16 * tc + lr] = acc[tc][r];
    __syncthreads();
    if (tid < 128) {
        int r = tid & 63;
        const float* av = sA + ((tid < 64) ? 0 : 128);
        float s = 0.f;
#pragma unroll 4
        for (int c = 0; c < 128; ++c) s += tile[r][c] * av[c];
        ((tid < 64) ? ssrc : sdst)[(bt << 10) + i0 + r] = s;
    }
    {
        int c = tid & 127, hh2 = tid >> 7;
        u16 tmp[32];
#pragma unroll
        for (int j = 0; j < 32; ++j) tmp[j] = f2b(tile[32 * hh2 + j][c]);
        u16* dst = WhT + (((size_t)(bt << 7) + c) << 10) + i0 + 32 * hh2;
#pragma unroll
        for (int q = 0; q < 4; ++q) *(short8*)(dst + 8 * q) = *(const short8*)(tmp + 8 * q);
    }
}

// ---------------- attention: LDS-staged B double-buffer, M=32/wave, ones-MFMA denom ----------------
__global__ __launch_bounds__(256, 2) void k_attn(const u16* __restrict__ WhT, const float* __restrict__ ssrc,
                                                 const float* __restrict__ sdst, const u32* __restrict__ bm,
                                                 u16* __restrict__ hout) {
    __shared__ __align__(16) u16 Bbuf[2][8192];     // 2 x 16KB: chunk = 2 jc (64 j-rows x 128 cols)
    __shared__ __align__(16) float Ej[1024];
    __shared__ __align__(16) float Fj[1024];
    __shared__ u32 bml[32 * 132];                   // [wd][blockrow], pad 132
    int bt = blockIdx.x >> 3, i0b = (blockIdx.x & 7) << 7;
    int b = bt >> 4;
    int tid = threadIdx.x, wv = tid >> 6, l = tid & 63;
    int lr = l & 15, lg = l >> 4;

    for (int k = tid; k < 1024; k += 256) {
        float sdv = sdst[(bt << 10) + k];
        Ej[k] = __expf(sdv);
        Fj[k] = __expf(0.2f * sdv);
    }
    for (int k = tid; k < 4096; k += 256) {
        int r = k >> 5, wd = k & 31;
        bml[wd * 132 + r] = bm[(((size_t)(b << 10) + i0b + r) << 5) + wd];
    }
    const u16* wbase = WhT + ((size_t)bt << 17);
    {   // stage chunk 0
        int u0 = wv << 2;
#pragma unroll
        for (int p = 0; p < 4; ++p) {
            int u = u0 + p;
            const u16* gs = wbase + ((((u & 7) << 4) + lr) << 10) + ((u >> 3) << 5) + 8 * lg;
            gload_lds16(gs, Bbuf[0] + u * 512);
        }
    }
    int rb = i0b + (wv << 5);
    float si0 = ssrc[(bt << 10) + rb + lr];
    float si1 = ssrc[(bt << 10) + rb + 16 + lr];
    float Ei0 = __expf(si0), Fi0 = __expf(0.2f * si0);
    float Ei1 = __expf(si1), Fi1 = __expf(0.2f * si1);
    f32x4 acc[2][8];
#pragma unroll
    for (int rt = 0; rt < 2; ++rt)
#pragma unroll
        for (int tc = 0; tc < 8; ++tc) acc[rt][tc] = (f32x4){0.f, 0.f, 0.f, 0.f};
    f32x4 accd[2];
    accd[0] = (f32x4){0.f, 0.f, 0.f, 0.f};
    accd[1] = (f32x4){0.f, 0.f, 0.f, 0.f};
    short8 bone;
#pragma unroll
    for (int e = 0; e < 8; ++e) bone[e] = (short)0x3F80;   // bf16 1.0
    int rl0 = (wv << 5) + lr;
    __syncthreads();

    for (int c = 0; c < 16; ++c) {
        int cur = c & 1;
        if (c < 15) {
            int u0 = wv << 2;
#pragma unroll
            for (int p = 0; p < 4; ++p) {
                int u = u0 + p;
                const u16* gs = wbase + ((((u & 7) << 4) + lr) << 10) + ((2 * (c + 1) + (u >> 3)) << 5) + 8 * lg;
                gload_lds16(gs, Bbuf[cur ^ 1] + u * 512);
            }
        }
#pragma unroll
        for (int jcl = 0; jcl < 2; ++jcl) {
            int jc = 2 * c + jcl;
            short8 bfr[8];
#pragma unroll
            for (int tc = 0; tc < 8; ++tc)
                bfr[tc] = *(const short8*)(Bbuf[cur] + ((((jcl << 3) + tc) << 6) + l) * 8);
            const float* ejp = Ej + (jc << 5) + (lg << 3);
            const float* fjp = Fj + (jc << 5) + (lg << 3);
            float4 e0 = *(const float4*)ejp, e1 = *(const float4*)(ejp + 4);
            float4 f0 = *(const float4*)fjp, f1 = *(const float4*)(fjp + 4);
            u32 w0 = bml[jc * 132 + rl0];
            u32 w1 = bml[jc * 132 + rl0 + 16];
            AFu af0, af1;
            {
                u32 byt = (w0 >> (lg << 3)) & 0xFFu;
                float pA[8] = {fmaxf(Ei0 * e0.x, Fi0 * f0.x), fmaxf(Ei0 * e0.y, Fi0 * f0.y),
                               fmaxf(Ei0 * e0.z, Fi0 * f0.z), fmaxf(Ei0 * e0.w, Fi0 * f0.w),
                               fmaxf(Ei0 * e1.x, Fi0 * f1.x), fmaxf(Ei0 * e1.y, Fi0 * f1.y),
                               fmaxf(Ei0 * e1.z, Fi0 * f1.z), fmaxf(Ei0 * e1.w, Fi0 * f1.w)};
#pragma unroll
                for (int q = 0; q < 4; ++q) {
                    u32 m0 = (u32)(-(int)((byt >> (2 * q)) & 1u));
                    u32 m1 = (u32)(-(int)((byt >> (2 * q + 1)) & 1u));
                    float p0 = __uint_as_float(__float_as_uint(pA[2 * q]) & m0);
                    float p1 = __uint_as_float(__float_as_uint(pA[2 * q + 1]) & m1);
                    asm("v_cvt_pk_bf16_f32 %0, %1, %2" : "=v"(af0.u[q]) : "v"(p0), "v"(p1));
                }
            }
            {
                u32 byt = (w1 >> (lg << 3)) & 0xFFu;
                float pA[8] = {fmaxf(Ei1 * e0.x, Fi1 * f0.x), fmaxf(Ei1 * e0.y, Fi1 * f0.y),
                               fmaxf(Ei1 * e0.z, Fi1 * f0.z), fmaxf(Ei1 * e0.w, Fi1 * f0.w),
                               fmaxf(Ei1 * e1.x, Fi1 * f1.x), fmaxf(Ei1 * e1.y, Fi1 * f1.y),
                               fmaxf(Ei1 * e1.z, Fi1 * f1.z), fmaxf(Ei1 * e1.w, Fi1 * f1.w)};
#pragma unroll
                for (int q = 0; q < 4; ++q) {
                    u32 m0 = (u32)(-(int)((byt >> (2 * q)) & 1u));
                    u32 m1 = (u32)(-(int)((byt >> (2 * q + 1)) & 1u));
                    float p0 = __uint_as_float(__float_as_uint(pA[2 * q]) & m0);
                    float p1 = __uint_as_float(__float_as_uint(pA[2 * q + 1]) & m1);
                    asm("v_cvt_pk_bf16_f32 %0, %1, %2" : "=v"(af1.u[q]) : "v"(p0), "v"(p1));
                }
            }
#pragma unroll
            for (int tc = 0; tc < 8; ++tc) {
                acc[0][tc] = __builtin_amdgcn_mfma_f32_16x16x32_bf16(af0.s, bfr[tc], acc[0][tc], 0, 0, 0);
                acc[1][tc] = __builtin_amdgcn_mfma_f32_16x16x32_bf16(af1.s, bfr[tc], acc[1][tc], 0, 0, 0);
            }
            accd[0] = __builtin_amdgcn_mfma_f32_16x16x32_bf16(af0.s, bone, accd[0], 0, 0, 0);
            accd[1] = __builtin_amdgcn_mfma_f32_16x16x32_bf16(af1.s, bone, accd[1], 0, 0, 0);
        }
        __syncthreads();   // drains vmcnt (prefetch) + orders buffer reuse
    }

#pragma unroll
    for (int rt = 0; rt < 2; ++rt) {
        float inv[4];
#pragma unroll
        for (int r = 0; r < 4; ++r) inv[r] = 1.f / accd[rt][r];   // every lane holds its rows' sums
        size_t obase = ((size_t)((bt << 10) + rb + (rt << 4))) << 7;
#pragma unroll
        for (int tc = 0; tc < 8; ++tc)
#pragma unroll
            for (int r = 0; r < 4; ++r) {
                float v = acc[rt][tc][r] * inv[r];
                v = v > 0.f ? v : (__expf(v) - 1.f);
                v = v > 0.f ? v : (__expf(v) - 1.f);
                hout[obase + ((size_t)((lg << 2) + r) << 7) + (tc << 4) + lr] = f2b(v);
            }
    }
}

// ---------------- Gx = seq @ W_ih^T + bias, written in MFMA-fragment order ----------------
__global__ __launch_bounds__(256) void k_gx(const u16* __restrict__ g, const u16* __restrict__ WihB,
                                            const float* __restrict__ bsum, u16* __restrict__ Gx) {
    int rm0 = blockIdx.x << 6;
    int bt = rm0 >> 10, n0 = rm0 & 1023;
    int b = bt >> 4, t = bt & 15;
    int tid = threadIdx.x, w = tid >> 6, l = tid & 63;
    int lr = l & 15, lg = l >> 4;
    const u16* ap = g + ((size_t)(rm0 + 16 * w + lr) << 7) + 8 * lg;
    f32x4 acc[16];
#pragma unroll
    for (int tc = 0; tc < 16; ++tc) acc[tc] = (f32x4){0.f, 0.f, 0.f, 0.f};
#pragma unroll
    for (int ch = 0; ch < 4; ++ch) {
        short8 af = *(const short8*)(ap + 32 * ch);
#pragma unroll
        for (int tc = 0; tc < 16; ++tc) {
            short8 bf = *(const short8*)(WihB + ((16 * tc + lr) << 7) + 32 * ch + 8 * lg);
            acc[tc] = __builtin_amdgcn_mfma_f32_16x16x32_bf16(af, bf, acc[tc], 0, 0, 0);
        }
    }
    // fragment layout: [t][grp][q(=tc pair)][lane] of 8 u16
    int grp = (b << 6) + (n0 >> 4) + w;
    u16* gdst = Gx + (size_t)t * 1048576 + (size_t)grp * 4096 + l * 8;
#pragma unroll
    for (int q = 0; q < 8; ++q) {
        short8 v;
#pragma unroll
        for (int r = 0; r < 4; ++r) {
            v[r]     = (short)f2b(acc[2 * q][r]     + bsum[((2 * q) << 4) + lr]);
            v[4 + r] = (short)f2b(acc[2 * q + 1][r] + bsum[((2 * q + 1) << 4) + lr]);
        }
        *(short8*)(gdst + q * 512) = v;
    }
}

// ---------------- LSTM recurrence (MFMA, 16 nodes/block) + fused MLP ----------------
__global__ __launch_bounds__(64, 1) void k_lstm(const u16* __restrict__ Gx, const u16* __restrict__ WhhB,
                                                const float* __restrict__ Wo1, const float* __restrict__ bo1,
                                                const float* __restrict__ Wo2, const float* __restrict__ bo2,
                                                float* __restrict__ out) {
    __shared__ u16 hls[16 * 72];
    __shared__ float hf[16 * 65];
    __shared__ float wo1[64 * 32];
    __shared__ float wo2[32];
    int grp = blockIdx.x;
    int m0 = grp << 4;
    int l = threadIdx.x, lr = l & 15, lg = l >> 4;
    for (int k = l; k < 64 * 32; k += 64) wo1[k] = Wo1[k];
    if (l < 32) wo2[l] = Wo2[l];
    for (int k = l; k < 16 * 72; k += 64) hls[k] = 0;
    short8 bh[16][2];
#pragma unroll
    for (int tc = 0; tc < 16; ++tc)
#pragma unroll
        for (int ch = 0; ch < 2; ++ch)
            bh[tc][ch] = *(const short8*)(WhhB + ((16 * tc + lr) << 6) + 32 * ch + 8 * lg);
    float cst[4][4], hreg[4][4];
#pragma unroll
    for (int r = 0; r < 4; ++r)
#pragma unroll
        for (int q = 0; q < 4; ++q) cst[r][q] = 0.f;
    const u16* gp = Gx + ((size_t)grp << 12) + l * 8;
    short8 gx0[8], gx1[8];
#pragma unroll
    for (int q = 0; q < 8; ++q) gx0[q] = *(const short8*)(gp + q * 512);
    __syncthreads();
#pragma unroll
    for (int t = 0; t < TT; ++t) {
        if (t < 15) {     // prefetch next step's Gx fragments
#pragma unroll
            for (int q = 0; q < 8; ++q) {
                short8 v = *(const short8*)(gp + (size_t)(t + 1) * 1048576 + q * 512);
                if (t & 1) gx0[q] = v; else gx1[q] = v;
            }
        }
        f32x4 acc[16];
#pragma unroll
        for (int q = 0; q < 8; ++q) {
            short8 v = (t & 1) ? gx1[q] : gx0[q];
#pragma unroll
            for (int r = 0; r < 4; ++r) {
                acc[2 * q][r]     = b2f((u16)v[r]);
                acc[2 * q + 1][r] = b2f((u16)v[4 + r]);
            }
        }
#pragma unroll
        for (int ch = 0; ch < 2; ++ch) {
            short8 af = *(const short8*)(hls + lr * 72 + 32 * ch + 8 * lg);
#pragma unroll
            for (int tc = 0; tc < 16; ++tc)
                acc[tc] = __builtin_amdgcn_mfma_f32_16x16x32_bf16(af, bh[tc][ch], acc[tc], 0, 0, 0);
        }
#pragma unroll
        for (int r = 0; r < 4; ++r)
#pragma unroll
            for (int q = 0; q < 4; ++q) {
                float iv = fsig(acc[q][r]);
                float fv = fsig(acc[q + 4][r]);
                float gv = ftanh(acc[q + 8][r]);
                float ov = fsig(acc[q + 12][r]);
                float cn = __builtin_fmaf(fv, cst[r][q], iv * gv);
                cst[r][q] = cn;
                hreg[r][q] = ov * ftanh(cn);
            }
        __syncthreads();
#pragma unroll
        for (int r = 0; r < 4; ++r)
#pragma unroll
            for (int q = 0; q < 4; ++q)
                hls[(4 * lg + r) * 72 + 16 * q + lr] = f2b(hreg[r][q]);
        __syncthreads();
    }
#pragma unroll
    for (int r = 0; r < 4; ++r)
#pragma unroll
        for (int q = 0; q < 4; ++q)
            hf[(4 * lg + r) * 65 + 16 * q + lr] = hreg[r][q];
    __syncthreads();
    {
        int r = l & 15, p = l >> 4;
        float hid[8];
#pragma unroll
        for (int q = 0; q < 8; ++q) hid[q] = bo1[8 * p + q];
        for (int j = 0; j < 64; ++j) {
            float hv = hf[r * 65 + j];
#pragma unroll
            for (int q = 0; q < 8; ++q) hid[q] += hv * wo1[j * 32 + 8 * p + q];
        }
        float po = 0.f;
#pragma unroll
        for (int q = 0; q < 8; ++q) po += fmaxf(hid[q], 0.f) * wo2[8 * p + q];
        po += __shfl_xor(po, 16);
        po += __shfl_xor(po, 32);
        if (p == 0) out[m0 + r] = po + bo2[0];
    }
}

extern "C" void kernel_launch(void* const* d_in, const int* in_sizes, int n_in,
                              void* d_out, int out_size, void* d_ws, size_t ws_size,
                              hipStream_t stream) {
    const float* x    = (const float*)d_in[0];
    const int*   adj  = (const int*)d_in[1];
    const float* W1   = (const float*)d_in[2];
    const float* a1   = (const float*)d_in[3];
    const float* W2   = (const float*)d_in[4];
    const float* a2   = (const float*)d_in[5];
    const float* W_ih = (const float*)d_in[6];
    const float* W_hh = (const float*)d_in[7];
    const float* b_ih = (const float*)d_in[8];
    const float* b_hh = (const float*)d_in[9];
    const float* Wo1  = (const float*)d_in[10];
    const float* bo1  = (const float*)d_in[11];
    const float* Wo2  = (const float*)d_in[12];
    const float* bo2  = (const float*)d_in[13];
    float* out = (float*)d_out;

    char* w = (char*)d_ws;
    const size_t SLOT = (size_t)8388608 * sizeof(u16);   // 16.78 MB
    u16* A  = (u16*)w;
    u16* Bf = (u16*)(w + SLOT);
    u16* C  = (u16*)(w + 2 * SLOT);
    char* sm = w + 3 * SLOT;
    float* s1s = (float*)sm;
    float* s1d = s1s + 65536;
    float* s2s = s1d + 65536;
    float* s2d = s2s + 65536;
    u32* BM  = (u32*)(s2d + 65536);      // 131072 words (512 KB)
    u16* W1T = (u16*)(BM + 131072);      // 4096
    u16* W2T = W1T + 4096;               // 16384
    u16* WihB = W2T + 16384;             // 32768
    u16* WhhB = WihB + 32768;            // 16384
    float* BS = (float*)(WhhB + 16384);  // 256
    u16* Gx = Bf;                        // spans Bf..C (33.55 MB), used after both are dead

    k_pre<<<1, 256, 0, stream>>>(W1, W2, W_ih, W_hh, b_ih, b_hh, W1T, W2T, WihB, WhhB, BS);
    k_mask<<<256, 256, 0, stream>>>(adj, (unsigned long long*)BM);
    k_projA<<<1024, 256, 0, stream>>>(x, W1T, a1, A, s1s, s1d);
    k_attn<<<512, 256, 0, stream>>>(A, s1s, s1d, BM, Bf);
    k_projB<<<1024, 256, 0, stream>>>(Bf, W2T, a2, C, s2s, s2d);
    k_attn<<<512, 256, 0, stream>>>(C, s2s, s2d, BM, A);
    k_gx<<<1024, 256, 0, stream>>>(A, WihB, BS, Gx);
    k_lstm<<<256, 64, 0, stream>>>(Gx, WhhB, Wo1, bo1, Wo2, bo2, out);
}

// Round 6
// 199.835 us; speedup vs baseline: 21.1974x; 1.2420x over previous
//
#include <hip/hip_runtime.h>
#include <hip/hip_bf16.h>
#include <math.h>

#define BB 4
#define NN 1024
#define TT 16
#define FIN 32
#define HH 128
#define LH 64
#define MLPH 32

typedef __attribute__((ext_vector_type(8))) short short8;
typedef __attribute__((ext_vector_type(4))) float f32x4;
typedef unsigned short u16;
typedef unsigned int u32;

union AFu { u32 u[4]; short8 s; };

__device__ __forceinline__ u16 f2b(float f) {
    union { float f; u32 u; } v; v.f = f;
    u32 u = v.u;
    return (u16)((u + 0x7FFFu + ((u >> 16) & 1u)) >> 16);
}
__device__ __forceinline__ float b2f(u16 h) {
    union { u32 u; float f; } v; v.u = ((u32)h) << 16;
    return v.f;
}
__device__ __forceinline__ float frcp(float x) {
    float r; asm("v_rcp_f32 %0, %1" : "=v"(r) : "v"(x)); return r;
}
__device__ __forceinline__ float fsig(float x) {          // 1/(1+e^-x)
    return frcp(1.f + __expf(-x));
}
__device__ __forceinline__ float ftanh(float x) {         // 2*sig(2x)-1
    return __builtin_fmaf(2.f, frcp(1.f + __expf(-2.f * x)), -1.f);
}
__device__ __forceinline__ void gload_lds16(const void* g, void* l) {
    __builtin_amdgcn_global_load_lds((const __attribute__((address_space(1))) unsigned int*)g,
                                     (__attribute__((address_space(3))) unsigned int*)l, 16, 0, 0);
}

// ---------------- precompute (parallel): bf16 weight layouts + fused bias ----------------
__global__ __launch_bounds__(256) void k_pre(const float* __restrict__ W1, const float* __restrict__ W2,
                      const float* __restrict__ W_ih, const float* __restrict__ W_hh,
                      const float* __restrict__ b_ih, const float* __restrict__ b_hh,
                      u16* W1T, u16* W2T, u16* WihB, u16* WhhB, float* bsum) {
    int gi = blockIdx.x * 256 + threadIdx.x;     // 64 blocks -> 16384 threads
    for (int i = gi; i < 128 * 32; i += 16384) { int c = i >> 5, k = i & 31; W1T[i] = f2b(W1[k * 128 + c]); }
    for (int i = gi; i < 128 * 128; i += 16384) { int c = i >> 7, k = i & 127; W2T[i] = f2b(W2[k * 128 + c]); }
    for (int i = gi; i < 256 * 128; i += 16384) WihB[i] = f2b(W_ih[i]);
    for (int i = gi; i < 256 * 64; i += 16384) WhhB[i] = f2b(W_hh[i]);
    if (gi < 256) bsum[gi] = b_ih[gi] + b_hh[gi];
}

// ---------------- adjacency -> bitmask (1 bit per edge) ----------------
__global__ __launch_bounds__(256) void k_mask(const int* __restrict__ adj, unsigned long long* __restrict__ bm) {
    int gw = (blockIdx.x * 256 + threadIdx.x) >> 6;
    int lane = threadIdx.x & 63;
    for (int u = gw; u < (BB * NN * NN) / 64; u += 1024) {
        unsigned long long m = __ballot(adj[(size_t)u * 64 + lane] > 0);
        if (lane == 0) bm[u] = m;
    }
}

// ---------------- GAT layer-1 projection (MFMA): x -> Wh1^T bf16 + s vectors ----------------
__global__ __launch_bounds__(256) void k_projA(const float* __restrict__ x, const u16* __restrict__ W1T,
                                               const float* __restrict__ a1,
                                               u16* __restrict__ WhT, float* __restrict__ ssrc,
                                               float* __restrict__ sdst) {
    __shared__ float tile[64][132];
    __shared__ float sA[256];
    int bt = blockIdx.x >> 4, i0 = (blockIdx.x & 15) << 6;
    int b = bt >> 4, t = bt & 15;
    int tid = threadIdx.x, w = tid >> 6, l = tid & 63;
    int lr = l & 15, lg = l >> 4;
    sA[tid] = a1[tid];
    int i = i0 + 16 * w + lr;
    const float* xp = x + ((size_t)((b << 10) + i) * TT + t) * FIN + 8 * lg;
    float4 x0 = *(const float4*)xp;
    float4 x1 = *(const float4*)(xp + 4);
    short8 af;
    af[0] = (short)f2b(x0.x); af[1] = (short)f2b(x0.y); af[2] = (short)f2b(x0.z); af[3] = (short)f2b(x0.w);
    af[4] = (short)f2b(x1.x); af[5] = (short)f2b(x1.y); af[6] = (short)f2b(x1.z); af[7] = (short)f2b(x1.w);
    f32x4 zz = {0.f, 0.f, 0.f, 0.f};
#pragma unroll
    for (int tc = 0; tc < 8; ++tc) {
        short8 bf = *(const short8*)(W1T + ((16 * tc + lr) << 5) + 8 * lg);
        f32x4 d = __builtin_amdgcn_mfma_f32_16x16x32_bf16(af, bf, zz, 0, 0, 0);
#pragma unroll
        for (int r = 0; r < 4; ++r) tile[16 * w + 4 * lg + r][16 * tc + lr] = d[r];
    }
    __syncthreads();
    if (tid < 128) {
        int r = tid & 63;
        const float* av = sA + ((tid < 64) ? 0 : 128);
        float s = 0.f;
#pragma unroll 4
        for (int c = 0; c < 128; ++c) s += tile[r][c] * av[c];
        ((tid < 64) ? ssrc : sdst)[(bt << 10) + i0 + r] = s;
    }
    {
        int c = tid & 127, hh2 = tid >> 7;
        u16 tmp[32];
#pragma unroll
        for (int j = 0; j < 32; ++j) tmp[j] = f2b(tile[32 * hh2 + j][c]);
        u16* dst = WhT + (((size_t)(bt << 7) + c) << 10) + i0 + 32 * hh2;
#pragma unroll
        for (int q = 0; q < 4; ++q) *(short8*)(dst + 8 * q) = *(const short8*)(tmp + 8 * q);
    }
}

// ---------------- GAT layer-2 projection (MFMA): h1 bf16 -> Wh2^T bf16 + s vectors ----------------
__global__ __launch_bounds__(256) void k_projB(const u16* __restrict__ h1, const u16* __restrict__ W2T,
                                               const float* __restrict__ a2,
                                               u16* __restrict__ WhT, float* __restrict__ ssrc,
                                               float* __restrict__ sdst) {
    __shared__ float tile[64][132];
    __shared__ float sA[256];
    int bt = blockIdx.x >> 4, i0 = (blockIdx.x & 15) << 6;
    int tid = threadIdx.x, w = tid >> 6, l = tid & 63;
    int lr = l & 15, lg = l >> 4;
    sA[tid] = a2[tid];
    int i = i0 + 16 * w + lr;
    const u16* ap = h1 + (((size_t)(bt << 10) + i) << 7) + 8 * lg;
    f32x4 acc[8];
#pragma unroll
    for (int tc = 0; tc < 8; ++tc) acc[tc] = (f32x4){0.f, 0.f, 0.f, 0.f};
#pragma unroll
    for (int ch = 0; ch < 4; ++ch) {
        short8 af = *(const short8*)(ap + 32 * ch);
#pragma unroll
        for (int tc = 0; tc < 8; ++tc) {
            short8 bf = *(const short8*)(W2T + ((16 * tc + lr) << 7) + 32 * ch + 8 * lg);
            acc[tc] = __builtin_amdgcn_mfma_f32_16x16x32_bf16(af, bf, acc[tc], 0, 0, 0);
        }
    }
#pragma unroll
    for (int tc = 0; tc < 8; ++tc)
#pragma unroll
        for (int r = 0; r < 4; ++r) tile[16 * w + 4 * lg + r][16 * tc + lr] = acc[tc][r];
    __syncthreads();
    if (tid < 128) {
        int r = tid & 63;
        const float* av = sA + ((tid < 64) ? 0 : 128);
        float s = 0.f;
#pragma unroll 4
        for (int c = 0; c < 128; ++c) s += tile[r][c] * av[c];
        ((tid < 64) ? ssrc : sdst)[(bt << 10) + i0 + r] = s;
    }
    {
        int c = tid & 127, hh2 = tid >> 7;
        u16 tmp[32];
#pragma unroll
        for (int j = 0; j < 32; ++j) tmp[j] = f2b(tile[32 * hh2 + j][c]);
        u16* dst = WhT + (((size_t)(bt << 7) + c) << 10) + i0 + 32 * hh2;
#pragma unroll
        for (int q = 0; q < 4; ++q) *(short8*)(dst + 8 * q) = *(const short8*)(tmp + 8 * q);
    }
}

// ---------------- attention: LDS-staged B dbuf, M=32/wave, ones-MFMA denom.
// GX=true: fused epilogue computes Gx = elu2(h) @ W_ih^T + bias (layer-2 path, no h write).
template <bool GX>
__global__ __launch_bounds__(256, 2) void k_attn(const u16* __restrict__ WhT, const float* __restrict__ ssrc,
                                                 const float* __restrict__ sdst, const u32* __restrict__ bm,
                                                 u16* __restrict__ hout, const u16* __restrict__ WihB,
                                                 const float* __restrict__ bsum, u16* __restrict__ Gx) {
    __shared__ __align__(16) u16 Bbuf[2][8192];     // 2 x 16KB: chunk = 2 jc (64 j-rows x 128 cols)
    __shared__ __align__(16) float Ej[1024];
    __shared__ __align__(16) float Fj[1024];
    __shared__ u32 bml[32 * 132];                   // [wd][blockrow], pad 132
    int bt = blockIdx.x >> 3, i0b = (blockIdx.x & 7) << 7;
    int b = bt >> 4;
    int tid = threadIdx.x, wv = tid >> 6, l = tid & 63;
    int lr = l & 15, lg = l >> 4;

    for (int k = tid; k < 1024; k += 256) {
        float sdv = sdst[(bt << 10) + k];
        Ej[k] = __expf(sdv);
        Fj[k] = __expf(0.2f * sdv);
    }
    for (int k = tid; k < 4096; k += 256) {
        int r = k >> 5, wd = k & 31;
        bml[wd * 132 + r] = bm[(((size_t)(b << 10) + i0b + r) << 5) + wd];
    }
    const u16* wbase = WhT + ((size_t)bt << 17);
    {   // stage chunk 0
        int u0 = wv << 2;
#pragma unroll
        for (int p = 0; p < 4; ++p) {
            int u = u0 + p;
            const u16* gs = wbase + ((((u & 7) << 4) + lr) << 10) + ((u >> 3) << 5) + 8 * lg;
            gload_lds16(gs, Bbuf[0] + u * 512);
        }
    }
    int rb = i0b + (wv << 5);
    float si0 = ssrc[(bt << 10) + rb + lr];
    float si1 = ssrc[(bt << 10) + rb + 16 + lr];
    float Ei0 = __expf(si0), Fi0 = __expf(0.2f * si0);
    float Ei1 = __expf(si1), Fi1 = __expf(0.2f * si1);
    f32x4 acc[2][8];
#pragma unroll
    for (int rt = 0; rt < 2; ++rt)
#pragma unroll
        for (int tc = 0; tc < 8; ++tc) acc[rt][tc] = (f32x4){0.f, 0.f, 0.f, 0.f};
    f32x4 accd[2];
    accd[0] = (f32x4){0.f, 0.f, 0.f, 0.f};
    accd[1] = (f32x4){0.f, 0.f, 0.f, 0.f};
    short8 bone;
#pragma unroll
    for (int e = 0; e < 8; ++e) bone[e] = (short)0x3F80;   // bf16 1.0
    int rl0 = (wv << 5) + lr;
    __syncthreads();

    for (int c = 0; c < 16; ++c) {
        int cur = c & 1;
        if (c < 15) {
            int u0 = wv << 2;
#pragma unroll
            for (int p = 0; p < 4; ++p) {
                int u = u0 + p;
                const u16* gs = wbase + ((((u & 7) << 4) + lr) << 10) + ((2 * (c + 1) + (u >> 3)) << 5) + 8 * lg;
                gload_lds16(gs, Bbuf[cur ^ 1] + u * 512);
            }
        }
#pragma unroll
        for (int jcl = 0; jcl < 2; ++jcl) {
            int jc = 2 * c + jcl;
            short8 bfr[8];
#pragma unroll
            for (int tc = 0; tc < 8; ++tc)
                bfr[tc] = *(const short8*)(Bbuf[cur] + ((((jcl << 3) + tc) << 6) + l) * 8);
            const float* ejp = Ej + (jc << 5) + (lg << 3);
            const float* fjp = Fj + (jc << 5) + (lg << 3);
            float4 e0 = *(const float4*)ejp, e1 = *(const float4*)(ejp + 4);
            float4 f0 = *(const float4*)fjp, f1 = *(const float4*)(fjp + 4);
            u32 w0 = bml[jc * 132 + rl0];
            u32 w1 = bml[jc * 132 + rl0 + 16];
            AFu af0, af1;
            {
                u32 byt = (w0 >> (lg << 3)) & 0xFFu;
                float pA[8] = {fmaxf(Ei0 * e0.x, Fi0 * f0.x), fmaxf(Ei0 * e0.y, Fi0 * f0.y),
                               fmaxf(Ei0 * e0.z, Fi0 * f0.z), fmaxf(Ei0 * e0.w, Fi0 * f0.w),
                               fmaxf(Ei0 * e1.x, Fi0 * f1.x), fmaxf(Ei0 * e1.y, Fi0 * f1.y),
                               fmaxf(Ei0 * e1.z, Fi0 * f1.z), fmaxf(Ei0 * e1.w, Fi0 * f1.w)};
#pragma unroll
                for (int q = 0; q < 4; ++q) {
                    u32 m0 = (u32)(-(int)((byt >> (2 * q)) & 1u));
                    u32 m1 = (u32)(-(int)((byt >> (2 * q + 1)) & 1u));
                    float p0 = __uint_as_float(__float_as_uint(pA[2 * q]) & m0);
                    float p1 = __uint_as_float(__float_as_uint(pA[2 * q + 1]) & m1);
                    asm("v_cvt_pk_bf16_f32 %0, %1, %2" : "=v"(af0.u[q]) : "v"(p0), "v"(p1));
                }
            }
            {
                u32 byt = (w1 >> (lg << 3)) & 0xFFu;
                float pA[8] = {fmaxf(Ei1 * e0.x, Fi1 * f0.x), fmaxf(Ei1 * e0.y, Fi1 * f0.y),
                               fmaxf(Ei1 * e0.z, Fi1 * f0.z), fmaxf(Ei1 * e0.w, Fi1 * f0.w),
                               fmaxf(Ei1 * e1.x, Fi1 * f1.x), fmaxf(Ei1 * e1.y, Fi1 * f1.y),
                               fmaxf(Ei1 * e1.z, Fi1 * f1.z), fmaxf(Ei1 * e1.w, Fi1 * f1.w)};
#pragma unroll
                for (int q = 0; q < 4; ++q) {
                    u32 m0 = (u32)(-(int)((byt >> (2 * q)) & 1u));
                    u32 m1 = (u32)(-(int)((byt >> (2 * q + 1)) & 1u));
                    float p0 = __uint_as_float(__float_as_uint(pA[2 * q]) & m0);
                    float p1 = __uint_as_float(__float_as_uint(pA[2 * q + 1]) & m1);
                    asm("v_cvt_pk_bf16_f32 %0, %1, %2" : "=v"(af1.u[q]) : "v"(p0), "v"(p1));
                }
            }
#pragma unroll
            for (int tc = 0; tc < 8; ++tc) {
                acc[0][tc] = __builtin_amdgcn_mfma_f32_16x16x32_bf16(af0.s, bfr[tc], acc[0][tc], 0, 0, 0);
                acc[1][tc] = __builtin_amdgcn_mfma_f32_16x16x32_bf16(af1.s, bfr[tc], acc[1][tc], 0, 0, 0);
            }
            accd[0] = __builtin_amdgcn_mfma_f32_16x16x32_bf16(af0.s, bone, accd[0], 0, 0, 0);
            accd[1] = __builtin_amdgcn_mfma_f32_16x16x32_bf16(af1.s, bone, accd[1], 0, 0, 0);
        }
        __syncthreads();   // drains vmcnt (prefetch) + orders buffer reuse
    }
    // After the final barrier all waves are done with Bbuf -> reusable as wave-private h tile.

    if (!GX) {
#pragma unroll
        for (int rt = 0; rt < 2; ++rt) {
            float inv[4];
#pragma unroll
            for (int r = 0; r < 4; ++r) inv[r] = 1.f / accd[rt][r];
            size_t obase = ((size_t)((bt << 10) + rb + (rt << 4))) << 7;
#pragma unroll
            for (int tc = 0; tc < 8; ++tc)
#pragma unroll
                for (int r = 0; r < 4; ++r) {
                    float v = acc[rt][tc][r] * inv[r];
                    v = v > 0.f ? v : (__expf(v) - 1.f);
                    v = v > 0.f ? v : (__expf(v) - 1.f);
                    hout[obase + ((size_t)((lg << 2) + r) << 7) + (tc << 4) + lr] = f2b(v);
                }
        }
    } else {
        // h (32 rows x 128 cols bf16) -> wave-private swizzled LDS tile
        char* hb = (char*)(&Bbuf[0][0]) + (wv << 13);   // 8 KB per wave
#pragma unroll
        for (int rt = 0; rt < 2; ++rt) {
            float inv[4];
#pragma unroll
            for (int r = 0; r < 4; ++r) inv[r] = 1.f / accd[rt][r];
#pragma unroll
            for (int tc = 0; tc < 8; ++tc)
#pragma unroll
                for (int r = 0; r < 4; ++r) {
                    float v = acc[rt][tc][r] * inv[r];
                    v = v > 0.f ? v : (__expf(v) - 1.f);
                    v = v > 0.f ? v : (__expf(v) - 1.f);
                    int row = (rt << 4) + (lg << 2) + r;
                    int col = (tc << 4) + lr;
                    *(u16*)(hb + (row << 8) + ((col << 1) ^ ((row & 7) << 4))) = f2b(v);
                }
        }
        int t = bt & 15;
        // Gx = h @ W_ih^T + bias, per 16-row tile, written in LSTM fragment order
#pragma unroll
        for (int rt = 0; rt < 2; ++rt) {
            f32x4 accg[16];
#pragma unroll
            for (int tc = 0; tc < 16; ++tc) accg[tc] = (f32x4){0.f, 0.f, 0.f, 0.f};
#pragma unroll
            for (int ch = 0; ch < 4; ++ch) {
                int row = (rt << 4) + lr;
                short8 af2 = *(const short8*)(hb + (row << 8) + (((ch << 6) + (lg << 4)) ^ ((lr & 7) << 4)));
#pragma unroll
                for (int tc = 0; tc < 16; ++tc) {
                    short8 bf = *(const short8*)(WihB + ((16 * tc + lr) << 7) + (ch << 5) + 8 * lg);
                    accg[tc] = __builtin_amdgcn_mfma_f32_16x16x32_bf16(af2, bf, accg[tc], 0, 0, 0);
                }
            }
            int node = i0b + (wv << 5) + (rt << 4);
            int grp = (b << 6) + (node >> 4);
            u16* gdst = Gx + (size_t)t * 1048576 + (size_t)grp * 4096 + l * 8;
#pragma unroll
            for (int q = 0; q < 8; ++q) {
                short8 v;
#pragma unroll
                for (int r = 0; r < 4; ++r) {
                    v[r]     = (short)f2b(accg[2 * q][r]     + bsum[((2 * q) << 4) + lr]);
                    v[4 + r] = (short)f2b(accg[2 * q + 1][r] + bsum[((2 * q + 1) << 4) + lr]);
                }
                *(short8*)(gdst + q * 512) = v;
            }
        }
    }
}

// ---------------- LSTM recurrence (MFMA, 16 nodes/block) + fused MLP ----------------
__global__ __launch_bounds__(64, 1) void k_lstm(const u16* __restrict__ Gx, const u16* __restrict__ WhhB,
                                                const float* __restrict__ Wo1, const float* __restrict__ bo1,
                                                const float* __restrict__ Wo2, const float* __restrict__ bo2,
                                                float* __restrict__ out) {
    __shared__ u16 hls[16 * 72];
    __shared__ float hf[16 * 65];
    __shared__ float wo1[64 * 32];
    __shared__ float wo2[32];
    int grp = blockIdx.x;
    int m0 = grp << 4;
    int l = threadIdx.x, lr = l & 15, lg = l >> 4;
    for (int k = l; k < 64 * 32; k += 64) wo1[k] = Wo1[k];
    if (l < 32) wo2[l] = Wo2[l];
    for (int k = l; k < 16 * 72; k += 64) hls[k] = 0;
    short8 bh[16][2];
#pragma unroll
    for (int tc = 0; tc < 16; ++tc)
#pragma unroll
        for (int ch = 0; ch < 2; ++ch)
            bh[tc][ch] = *(const short8*)(WhhB + ((16 * tc + lr) << 6) + 32 * ch + 8 * lg);
    float cst[4][4], hreg[4][4];
#pragma unroll
    for (int r = 0; r < 4; ++r)
#pragma unroll
        for (int q = 0; q < 4; ++q) cst[r][q] = 0.f;
    const u16* gp = Gx + ((size_t)grp << 12) + l * 8;
    short8 gx0[8], gx1[8];
#pragma unroll
    for (int q = 0; q < 8; ++q) gx0[q] = *(const short8*)(gp + q * 512);
    __syncthreads();
#pragma unroll
    for (int t = 0; t < TT; ++t) {
        if (t < 15) {     // prefetch next step's Gx fragments
#pragma unroll
            for (int q = 0; q < 8; ++q) {
                short8 v = *(const short8*)(gp + (size_t)(t + 1) * 1048576 + q * 512);
                if (t & 1) gx0[q] = v; else gx1[q] = v;
            }
        }
        f32x4 acc[16];
#pragma unroll
        for (int q = 0; q < 8; ++q) {
            short8 v = (t & 1) ? gx1[q] : gx0[q];
#pragma unroll
            for (int r = 0; r < 4; ++r) {
                acc[2 * q][r]     = b2f((u16)v[r]);
                acc[2 * q + 1][r] = b2f((u16)v[4 + r]);
            }
        }
#pragma unroll
        for (int ch = 0; ch < 2; ++ch) {
            short8 af = *(const short8*)(hls + lr * 72 + 32 * ch + 8 * lg);
#pragma unroll
            for (int tc = 0; tc < 16; ++tc)
                acc[tc] = __builtin_amdgcn_mfma_f32_16x16x32_bf16(af, bh[tc][ch], acc[tc], 0, 0, 0);
        }
#pragma unroll
        for (int r = 0; r < 4; ++r)
#pragma unroll
            for (int q = 0; q < 4; ++q) {
                float iv = fsig(acc[q][r]);
                float fv = fsig(acc[q + 4][r]);
                float gv = ftanh(acc[q + 8][r]);
                float ov = fsig(acc[q + 12][r]);
                float cn = __builtin_fmaf(fv, cst[r][q], iv * gv);
                cst[r][q] = cn;
                hreg[r][q] = ov * ftanh(cn);
            }
        __syncthreads();
#pragma unroll
        for (int r = 0; r < 4; ++r)
#pragma unroll
            for (int q = 0; q < 4; ++q)
                hls[(4 * lg + r) * 72 + 16 * q + lr] = f2b(hreg[r][q]);
        __syncthreads();
    }
#pragma unroll
    for (int r = 0; r < 4; ++r)
#pragma unroll
        for (int q = 0; q < 4; ++q)
            hf[(4 * lg + r) * 65 + 16 * q + lr] = hreg[r][q];
    __syncthreads();
    {
        int r = l & 15, p = l >> 4;
        float hid[8];
#pragma unroll
        for (int q = 0; q < 8; ++q) hid[q] = bo1[8 * p + q];
        for (int j = 0; j < 64; ++j) {
            float hv = hf[r * 65 + j];
#pragma unroll
            for (int q = 0; q < 8; ++q) hid[q] += hv * wo1[j * 32 + 8 * p + q];
        }
        float po = 0.f;
#pragma unroll
        for (int q = 0; q < 8; ++q) po += fmaxf(hid[q], 0.f) * wo2[8 * p + q];
        po += __shfl_xor(po, 16);
        po += __shfl_xor(po, 32);
        if (p == 0) out[m0 + r] = po + bo2[0];
    }
}

extern "C" void kernel_launch(void* const* d_in, const int* in_sizes, int n_in,
                              void* d_out, int out_size, void* d_ws, size_t ws_size,
                              hipStream_t stream) {
    const float* x    = (const float*)d_in[0];
    const int*   adj  = (const int*)d_in[1];
    const float* W1   = (const float*)d_in[2];
    const float* a1   = (const float*)d_in[3];
    const float* W2   = (const float*)d_in[4];
    const float* a2   = (const float*)d_in[5];
    const float* W_ih = (const float*)d_in[6];
    const float* W_hh = (const float*)d_in[7];
    const float* b_ih = (const float*)d_in[8];
    const float* b_hh = (const float*)d_in[9];
    const float* Wo1  = (const float*)d_in[10];
    const float* bo1  = (const float*)d_in[11];
    const float* Wo2  = (const float*)d_in[12];
    const float* bo2  = (const float*)d_in[13];
    float* out = (float*)d_out;

    char* w = (char*)d_ws;
    const size_t SLOT = (size_t)8388608 * sizeof(u16);   // 16.78 MB
    u16* A  = (u16*)w;
    u16* Bf = (u16*)(w + SLOT);
    u16* C  = (u16*)(w + 2 * SLOT);
    char* sm = w + 3 * SLOT;
    float* s1s = (float*)sm;
    float* s1d = s1s + 65536;
    float* s2s = s1d + 65536;
    float* s2d = s2s + 65536;
    u32* BM  = (u32*)(s2d + 65536);      // 131072 words (512 KB)
    u16* W1T = (u16*)(BM + 131072);      // 4096
    u16* W2T = W1T + 4096;               // 16384
    u16* WihB = W2T + 16384;             // 32768
    u16* WhhB = WihB + 32768;            // 16384
    float* BS = (float*)(WhhB + 16384);  // 256
    u16* Gx = Bf;                        // Bf dead after projB; Gx spans Bf..C (33.55 MB)

    k_pre<<<64, 256, 0, stream>>>(W1, W2, W_ih, W_hh, b_ih, b_hh, W1T, W2T, WihB, WhhB, BS);
    k_mask<<<256, 256, 0, stream>>>(adj, (unsigned long long*)BM);
    k_projA<<<1024, 256, 0, stream>>>(x, W1T, a1, A, s1s, s1d);
    k_attn<false><<<512, 256, 0, stream>>>(A, s1s, s1d, BM, Bf, nullptr, nullptr, nullptr);
    k_projB<<<1024, 256, 0, stream>>>(Bf, W2T, a2, C, s2s, s2d);
    k_attn<true><<<512, 256, 0, stream>>>(C, s2s, s2d, BM, nullptr, WihB, BS, Gx);
    k_lstm<<<256, 64, 0, stream>>>(Gx, WhhB, Wo1, bo1, Wo2, bo2, out);
}

// Round 7
// 183.934 us; speedup vs baseline: 23.0298x; 1.0864x over previous
//
#include <hip/hip_runtime.h>
#include <hip/hip_bf16.h>
#include <math.h>

#define BB 4
#define NN 1024
#define TT 16
#define FIN 32
#define HH 128
#define LH 64
#define MLPH 32

typedef __attribute__((ext_vector_type(8))) short short8;
typedef __attribute__((ext_vector_type(4))) float f32x4;
typedef unsigned short u16;
typedef unsigned int u32;

union AFu { u32 u[4]; short8 s; };

__device__ __forceinline__ u16 f2b(float f) {
    union { float f; u32 u; } v; v.f = f;
    u32 u = v.u;
    return (u16)((u + 0x7FFFu + ((u >> 16) & 1u)) >> 16);
}
__device__ __forceinline__ float b2f(u16 h) {
    union { u32 u; float f; } v; v.u = ((u32)h) << 16;
    return v.f;
}
__device__ __forceinline__ float frcp(float x) {
    float r; asm("v_rcp_f32 %0, %1" : "=v"(r) : "v"(x)); return r;
}
__device__ __forceinline__ float fsig(float x) {          // 1/(1+e^-x)
    return frcp(1.f + __expf(-x));
}
__device__ __forceinline__ float ftanh(float x) {         // 2*sig(2x)-1
    return __builtin_fmaf(2.f, frcp(1.f + __expf(-2.f * x)), -1.f);
}
__device__ __forceinline__ void gload_lds16(const void* g, void* l) {
    __builtin_amdgcn_global_load_lds((const __attribute__((address_space(1))) unsigned int*)g,
                                     (__attribute__((address_space(3))) unsigned int*)l, 16, 0, 0);
}

// ---------------- precompute (parallel): bf16 weight layouts + fused bias ----------------
__global__ __launch_bounds__(256) void k_pre(const float* __restrict__ W1, const float* __restrict__ W2,
                      const float* __restrict__ W_ih, const float* __restrict__ W_hh,
                      const float* __restrict__ b_ih, const float* __restrict__ b_hh,
                      u16* W1T, u16* W2T, u16* WihB, u16* WhhB, float* bsum) {
    int gi = blockIdx.x * 256 + threadIdx.x;     // 64 blocks -> 16384 threads
    for (int i = gi; i < 128 * 32; i += 16384) { int c = i >> 5, k = i & 31; W1T[i] = f2b(W1[k * 128 + c]); }
    for (int i = gi; i < 128 * 128; i += 16384) { int c = i >> 7, k = i & 127; W2T[i] = f2b(W2[k * 128 + c]); }
    for (int i = gi; i < 256 * 128; i += 16384) WihB[i] = f2b(W_ih[i]);
    for (int i = gi; i < 256 * 64; i += 16384) WhhB[i] = f2b(W_hh[i]);
    if (gi < 256) bsum[gi] = b_ih[gi] + b_hh[gi];
}

// ---------------- adjacency -> bitmask (1 bit per edge) ----------------
__global__ __launch_bounds__(256) void k_mask(const int* __restrict__ adj, unsigned long long* __restrict__ bm) {
    int gw = (blockIdx.x * 256 + threadIdx.x) >> 6;
    int lane = threadIdx.x & 63;
    for (int u = gw; u < (BB * NN * NN) / 64; u += 1024) {
        unsigned long long m = __ballot(adj[(size_t)u * 64 + lane] > 0);
        if (lane == 0) bm[u] = m;
    }
}

// WhT fragment-linear layout: [bt][chunk(16)][u=(jcl*8+tc)][lane(lg*16+lr)][8e]
// u16 offset = bt*131072 + chunk*8192 + u*512 + l*8
// element (col, j): tc=col>>4, lr=col&15, chunk=j>>6, jcl=(j>>5)&1, lg=(j>>3)&3, e=j&7

// ---------------- GAT layer-1 projection (MFMA): x -> Wh1 frag-linear + s vectors ----------------
__global__ __launch_bounds__(256) void k_projA(const float* __restrict__ x, const u16* __restrict__ W1T,
                                               const float* __restrict__ a1,
                                               u16* __restrict__ WhT, float* __restrict__ ssrc,
                                               float* __restrict__ sdst) {
    __shared__ float tile[64][132];
    __shared__ float sA[256];
    int bt = blockIdx.x >> 4, i0 = (blockIdx.x & 15) << 6;
    int b = bt >> 4, t = bt & 15;
    int tid = threadIdx.x, w = tid >> 6, l = tid & 63;
    int lr = l & 15, lg = l >> 4;
    sA[tid] = a1[tid];
    int i = i0 + 16 * w + lr;
    const float* xp = x + ((size_t)((b << 10) + i) * TT + t) * FIN + 8 * lg;
    float4 x0 = *(const float4*)xp;
    float4 x1 = *(const float4*)(xp + 4);
    short8 af;
    af[0] = (short)f2b(x0.x); af[1] = (short)f2b(x0.y); af[2] = (short)f2b(x0.z); af[3] = (short)f2b(x0.w);
    af[4] = (short)f2b(x1.x); af[5] = (short)f2b(x1.y); af[6] = (short)f2b(x1.z); af[7] = (short)f2b(x1.w);
    f32x4 zz = {0.f, 0.f, 0.f, 0.f};
#pragma unroll
    for (int tc = 0; tc < 8; ++tc) {
        short8 bf = *(const short8*)(W1T + ((16 * tc + lr) << 5) + 8 * lg);
        f32x4 d = __builtin_amdgcn_mfma_f32_16x16x32_bf16(af, bf, zz, 0, 0, 0);
#pragma unroll
        for (int r = 0; r < 4; ++r) tile[16 * w + 4 * lg + r][16 * tc + lr] = d[r];
    }
    __syncthreads();
    if (tid < 128) {
        int r = tid & 63;
        const float* av = sA + ((tid < 64) ? 0 : 128);
        float s = 0.f;
#pragma unroll 4
        for (int c = 0; c < 128; ++c) s += tile[r][c] * av[c];
        ((tid < 64) ? ssrc : sdst)[(bt << 10) + i0 + r] = s;
    }
    {   // write frag-linear: this block covers chunk = i0>>6, j-half hh2
        int c = tid & 127, hh2 = tid >> 7;     // col, jcl
        u16 tmp[32];
#pragma unroll
        for (int j = 0; j < 32; ++j) tmp[j] = f2b(tile[32 * hh2 + j][c]);
        int tc = c >> 4, lr2 = c & 15;
        u16* dst = WhT + (size_t)bt * 131072 + (i0 >> 6) * 8192 + ((hh2 << 3) + tc) * 512 + lr2 * 8;
#pragma unroll
        for (int lg2 = 0; lg2 < 4; ++lg2) *(short8*)(dst + lg2 * 128) = *(const short8*)(tmp + 8 * lg2);
    }
}

// ---------------- GAT layer-2 projection (MFMA): h1 frag-linear -> Wh2 frag-linear + s vectors ----------------
__global__ __launch_bounds__(256) void k_projB(const u16* __restrict__ h1, const u16* __restrict__ W2T,
                                               const float* __restrict__ a2,
                                               u16* __restrict__ WhT, float* __restrict__ ssrc,
                                               float* __restrict__ sdst) {
    __shared__ float tile[64][132];
    __shared__ float sA[256];
    int bt = blockIdx.x >> 4, i0 = (blockIdx.x & 15) << 6;
    int tid = threadIdx.x, w = tid >> 6, l = tid & 63;
    int lr = l & 15, lg = l >> 4;
    sA[tid] = a2[tid];
    // h1 A-fragment-linear: [bt][rtile][ch(4)][lane][8]
    const u16* ap = h1 + (size_t)bt * 131072 + ((i0 >> 4) + w) * 2048 + l * 8;
    f32x4 acc[8];
#pragma unroll
    for (int tc = 0; tc < 8; ++tc) acc[tc] = (f32x4){0.f, 0.f, 0.f, 0.f};
#pragma unroll
    for (int ch = 0; ch < 4; ++ch) {
        short8 af = *(const short8*)(ap + ch * 512);
#pragma unroll
        for (int tc = 0; tc < 8; ++tc) {
            short8 bf = *(const short8*)(W2T + ((16 * tc + lr) << 7) + 32 * ch + 8 * lg);
            acc[tc] = __builtin_amdgcn_mfma_f32_16x16x32_bf16(af, bf, acc[tc], 0, 0, 0);
        }
    }
#pragma unroll
    for (int tc = 0; tc < 8; ++tc)
#pragma unroll
        for (int r = 0; r < 4; ++r) tile[16 * w + 4 * lg + r][16 * tc + lr] = acc[tc][r];
    __syncthreads();
    if (tid < 128) {
        int r = tid & 63;
        const float* av = sA + ((tid < 64) ? 0 : 128);
        float s = 0.f;
#pragma unroll 4
        for (int c = 0; c < 128; ++c) s += tile[r][c] * av[c];
        ((tid < 64) ? ssrc : sdst)[(bt << 10) + i0 + r] = s;
    }
    {
        int c = tid & 127, hh2 = tid >> 7;
        u16 tmp[32];
#pragma unroll
        for (int j = 0; j < 32; ++j) tmp[j] = f2b(tile[32 * hh2 + j][c]);
        int tc = c >> 4, lr2 = c & 15;
        u16* dst = WhT + (size_t)bt * 131072 + (i0 >> 6) * 8192 + ((hh2 << 3) + tc) * 512 + lr2 * 8;
#pragma unroll
        for (int lg2 = 0; lg2 < 4; ++lg2) *(short8*)(dst + lg2 * 128) = *(const short8*)(tmp + 8 * lg2);
    }
}

// ---------------- attention: contiguous frag-linear B staging, M=32/wave, ones-MFMA denom.
// GX=true: fused Gx = elu2(h) @ W_ih^T + bias. GX=false: h out in A-fragment-linear layout.
template <bool GX>
__global__ __launch_bounds__(256, 2) void k_attn(const u16* __restrict__ WhT, const float* __restrict__ ssrc,
                                                 const float* __restrict__ sdst, const u32* __restrict__ bm,
                                                 u16* __restrict__ hout, const u16* __restrict__ WihB,
                                                 const float* __restrict__ bsum, u16* __restrict__ Gx) {
    __shared__ __align__(16) u16 Bbuf[2][8192];     // 2 x 16KB: chunk = 2 jc (64 j-rows x 128 cols)
    __shared__ __align__(16) float Ej[1024];
    __shared__ __align__(16) float Fj[1024];
    __shared__ u32 bml[32 * 132];                   // [wd][blockrow], pad 132
    int bt = blockIdx.x >> 3, i0b = (blockIdx.x & 7) << 7;
    int b = bt >> 4;
    int tid = threadIdx.x, wv = tid >> 6, l = tid & 63;
    int lr = l & 15, lg = l >> 4;

    for (int k = tid; k < 1024; k += 256) {
        float sdv = sdst[(bt << 10) + k];
        Ej[k] = __expf(sdv);
        Fj[k] = __expf(0.2f * sdv);
    }
    for (int k = tid; k < 4096; k += 256) {
        int r = k >> 5, wd = k & 31;
        bml[wd * 132 + r] = bm[(((size_t)(b << 10) + i0b + r) << 5) + wd];
    }
    const u16* wbase = WhT + (size_t)bt * 131072;
    {   // stage chunk 0 (contiguous 16KB stream)
        int u0 = wv << 2;
#pragma unroll
        for (int p = 0; p < 4; ++p) {
            int u = u0 + p;
            gload_lds16(wbase + u * 512 + l * 8, Bbuf[0] + u * 512);
        }
    }
    int rb = i0b + (wv << 5);
    float si0 = ssrc[(bt << 10) + rb + lr];
    float si1 = ssrc[(bt << 10) + rb + 16 + lr];
    float Ei0 = __expf(si0), Fi0 = __expf(0.2f * si0);
    float Ei1 = __expf(si1), Fi1 = __expf(0.2f * si1);
    f32x4 acc[2][8];
#pragma unroll
    for (int rt = 0; rt < 2; ++rt)
#pragma unroll
        for (int tc = 0; tc < 8; ++tc) acc[rt][tc] = (f32x4){0.f, 0.f, 0.f, 0.f};
    f32x4 accd[2];
    accd[0] = (f32x4){0.f, 0.f, 0.f, 0.f};
    accd[1] = (f32x4){0.f, 0.f, 0.f, 0.f};
    short8 bone;
#pragma unroll
    for (int e = 0; e < 8; ++e) bone[e] = (short)0x3F80;   // bf16 1.0
    int rl0 = (wv << 5) + lr;
    __syncthreads();

    for (int c = 0; c < 16; ++c) {
        int cur = c & 1;
        if (c < 15) {
            int u0 = wv << 2;
#pragma unroll
            for (int p = 0; p < 4; ++p) {
                int u = u0 + p;
                gload_lds16(wbase + (c + 1) * 8192 + u * 512 + l * 8, Bbuf[cur ^ 1] + u * 512);
            }
        }
#pragma unroll
        for (int jcl = 0; jcl < 2; ++jcl) {
            int jc = 2 * c + jcl;
            short8 bfr[8];
#pragma unroll
            for (int tc = 0; tc < 8; ++tc)
                bfr[tc] = *(const short8*)(Bbuf[cur] + ((((jcl << 3) + tc) << 6) + l) * 8);
            const float* ejp = Ej + (jc << 5) + (lg << 3);
            const float* fjp = Fj + (jc << 5) + (lg << 3);
            float4 e0 = *(const float4*)ejp, e1 = *(const float4*)(ejp + 4);
            float4 f0 = *(const float4*)fjp, f1 = *(const float4*)(fjp + 4);
            u32 w0 = bml[jc * 132 + rl0];
            u32 w1 = bml[jc * 132 + rl0 + 16];
            AFu af0, af1;
            {
                u32 byt = (w0 >> (lg << 3)) & 0xFFu;
                float pA[8] = {fmaxf(Ei0 * e0.x, Fi0 * f0.x), fmaxf(Ei0 * e0.y, Fi0 * f0.y),
                               fmaxf(Ei0 * e0.z, Fi0 * f0.z), fmaxf(Ei0 * e0.w, Fi0 * f0.w),
                               fmaxf(Ei0 * e1.x, Fi0 * f1.x), fmaxf(Ei0 * e1.y, Fi0 * f1.y),
                               fmaxf(Ei0 * e1.z, Fi0 * f1.z), fmaxf(Ei0 * e1.w, Fi0 * f1.w)};
#pragma unroll
                for (int q = 0; q < 4; ++q) {
                    u32 m0 = (u32)(-(int)((byt >> (2 * q)) & 1u));
                    u32 m1 = (u32)(-(int)((byt >> (2 * q + 1)) & 1u));
                    float p0 = __uint_as_float(__float_as_uint(pA[2 * q]) & m0);
                    float p1 = __uint_as_float(__float_as_uint(pA[2 * q + 1]) & m1);
                    asm("v_cvt_pk_bf16_f32 %0, %1, %2" : "=v"(af0.u[q]) : "v"(p0), "v"(p1));
                }
            }
            {
                u32 byt = (w1 >> (lg << 3)) & 0xFFu;
                float pA[8] = {fmaxf(Ei1 * e0.x, Fi1 * f0.x), fmaxf(Ei1 * e0.y, Fi1 * f0.y),
                               fmaxf(Ei1 * e0.z, Fi1 * f0.z), fmaxf(Ei1 * e0.w, Fi1 * f0.w),
                               fmaxf(Ei1 * e1.x, Fi1 * f1.x), fmaxf(Ei1 * e1.y, Fi1 * f1.y),
                               fmaxf(Ei1 * e1.z, Fi1 * f1.z), fmaxf(Ei1 * e1.w, Fi1 * f1.w)};
#pragma unroll
                for (int q = 0; q < 4; ++q) {
                    u32 m0 = (u32)(-(int)((byt >> (2 * q)) & 1u));
                    u32 m1 = (u32)(-(int)((byt >> (2 * q + 1)) & 1u));
                    float p0 = __uint_as_float(__float_as_uint(pA[2 * q]) & m0);
                    float p1 = __uint_as_float(__float_as_uint(pA[2 * q + 1]) & m1);
                    asm("v_cvt_pk_bf16_f32 %0, %1, %2" : "=v"(af1.u[q]) : "v"(p0), "v"(p1));
                }
            }
#pragma unroll
            for (int tc = 0; tc < 8; ++tc) {
                acc[0][tc] = __builtin_amdgcn_mfma_f32_16x16x32_bf16(af0.s, bfr[tc], acc[0][tc], 0, 0, 0);
                acc[1][tc] = __builtin_amdgcn_mfma_f32_16x16x32_bf16(af1.s, bfr[tc], acc[1][tc], 0, 0, 0);
            }
            accd[0] = __builtin_amdgcn_mfma_f32_16x16x32_bf16(af0.s, bone, accd[0], 0, 0, 0);
            accd[1] = __builtin_amdgcn_mfma_f32_16x16x32_bf16(af1.s, bone, accd[1], 0, 0, 0);
        }
        __syncthreads();   // drains vmcnt (prefetch) + orders buffer reuse
    }
    // After the final barrier Bbuf is dead -> wave-private 8KB h tile (XOR-swizzled).
    char* hb = (char*)(&Bbuf[0][0]) + (wv << 13);
#pragma unroll
    for (int rt = 0; rt < 2; ++rt) {
        float inv[4];
#pragma unroll
        for (int r = 0; r < 4; ++r) inv[r] = 1.f / accd[rt][r];
#pragma unroll
        for (int tc = 0; tc < 8; ++tc)
#pragma unroll
            for (int r = 0; r < 4; ++r) {
                float v = acc[rt][tc][r] * inv[r];
                v = v > 0.f ? v : (__expf(v) - 1.f);
                v = v > 0.f ? v : (__expf(v) - 1.f);
                int row = (rt << 4) + (lg << 2) + r;
                int col = (tc << 4) + lr;
                *(u16*)(hb + (row << 8) + ((col << 1) ^ ((row & 7) << 4))) = f2b(v);
            }
    }
    asm volatile("s_waitcnt lgkmcnt(0)" ::: "memory");
    __builtin_amdgcn_sched_barrier(0);

    if (!GX) {
        // h out in A-fragment-linear: [bt][rtile][ch][lane][8] -- contiguous 1KB stores
        int rtile0 = rb >> 4;
        u16* dstb = hout + (size_t)bt * 131072;
#pragma unroll
        for (int rt = 0; rt < 2; ++rt)
#pragma unroll
            for (int ch = 0; ch < 4; ++ch) {
                int row = (rt << 4) + lr;
                int colb = (ch << 5) + (lg << 3);
                short8 v = *(const short8*)(hb + (row << 8) + ((colb << 1) ^ ((row & 7) << 4)));
                *(short8*)(dstb + (size_t)(rtile0 + rt) * 2048 + ch * 512 + l * 8) = v;
            }
    } else {
        int t = bt & 15;
        // Gx = h @ W_ih^T + bias, per 16-row tile, written in LSTM fragment order
#pragma unroll
        for (int rt = 0; rt < 2; ++rt) {
            f32x4 accg[16];
#pragma unroll
            for (int tc = 0; tc < 16; ++tc) accg[tc] = (f32x4){0.f, 0.f, 0.f, 0.f};
#pragma unroll
            for (int ch = 0; ch < 4; ++ch) {
                int row = (rt << 4) + lr;
                short8 af2 = *(const short8*)(hb + (row << 8) + (((ch << 6) + (lg << 4)) ^ ((lr & 7) << 4)));
#pragma unroll
                for (int tc = 0; tc < 16; ++tc) {
                    short8 bf = *(const short8*)(WihB + ((16 * tc + lr) << 7) + (ch << 5) + 8 * lg);
                    accg[tc] = __builtin_amdgcn_mfma_f32_16x16x32_bf16(af2, bf, accg[tc], 0, 0, 0);
                }
            }
            int node = i0b + (wv << 5) + (rt << 4);
            int grp = (b << 6) + (node >> 4);
            u16* gdst = Gx + (size_t)t * 1048576 + (size_t)grp * 4096 + l * 8;
#pragma unroll
            for (int q = 0; q < 8; ++q) {
                short8 v;
#pragma unroll
                for (int r = 0; r < 4; ++r) {
                    v[r]     = (short)f2b(accg[2 * q][r]     + bsum[((2 * q) << 4) + lr]);
                    v[4 + r] = (short)f2b(accg[2 * q + 1][r] + bsum[((2 * q + 1) << 4) + lr]);
                }
                *(short8*)(gdst + q * 512) = v;
            }
        }
    }
}

// ---------------- LSTM recurrence (MFMA, 16 nodes/block) + fused MLP ----------------
__global__ __launch_bounds__(64, 1) void k_lstm(const u16* __restrict__ Gx, const u16* __restrict__ WhhB,
                                                const float* __restrict__ Wo1, const float* __restrict__ bo1,
                                                const float* __restrict__ Wo2, const float* __restrict__ bo2,
                                                float* __restrict__ out) {
    __shared__ u16 hls[16 * 72];
    __shared__ float hf[16 * 65];
    __shared__ float wo1[64 * 32];
    __shared__ float wo2[32];
    int grp = blockIdx.x;
    int m0 = grp << 4;
    int l = threadIdx.x, lr = l & 15, lg = l >> 4;
    for (int k = l; k < 64 * 32; k += 64) wo1[k] = Wo1[k];
    if (l < 32) wo2[l] = Wo2[l];
    for (int k = l; k < 16 * 72; k += 64) hls[k] = 0;
    short8 bh[16][2];
#pragma unroll
    for (int tc = 0; tc < 16; ++tc)
#pragma unroll
        for (int ch = 0; ch < 2; ++ch)
            bh[tc][ch] = *(const short8*)(WhhB + ((16 * tc + lr) << 6) + 32 * ch + 8 * lg);
    float cst[4][4], hreg[4][4];
#pragma unroll
    for (int r = 0; r < 4; ++r)
#pragma unroll
        for (int q = 0; q < 4; ++q) cst[r][q] = 0.f;
    const u16* gp = Gx + ((size_t)grp << 12) + l * 8;
    short8 gx0[8], gx1[8];
#pragma unroll
    for (int q = 0; q < 8; ++q) gx0[q] = *(const short8*)(gp + q * 512);
    __syncthreads();
#pragma unroll
    for (int t = 0; t < TT; ++t) {
        if (t < 15) {     // prefetch next step's Gx fragments
#pragma unroll
            for (int q = 0; q < 8; ++q) {
                short8 v = *(const short8*)(gp + (size_t)(t + 1) * 1048576 + q * 512);
                if (t & 1) gx0[q] = v; else gx1[q] = v;
            }
        }
        f32x4 acc[16];
#pragma unroll
        for (int q = 0; q < 8; ++q) {
            short8 v = (t & 1) ? gx1[q] : gx0[q];
#pragma unroll
            for (int r = 0; r < 4; ++r) {
                acc[2 * q][r]     = b2f((u16)v[r]);
                acc[2 * q + 1][r] = b2f((u16)v[4 + r]);
            }
        }
#pragma unroll
        for (int ch = 0; ch < 2; ++ch) {
            short8 af = *(const short8*)(hls + lr * 72 + 32 * ch + 8 * lg);
#pragma unroll
            for (int tc = 0; tc < 16; ++tc)
                acc[tc] = __builtin_amdgcn_mfma_f32_16x16x32_bf16(af, bh[tc][ch], acc[tc], 0, 0, 0);
        }
#pragma unroll
        for (int r = 0; r < 4; ++r)
#pragma unroll
            for (int q = 0; q < 4; ++q) {
                float iv = fsig(acc[q][r]);
                float fv = fsig(acc[q + 4][r]);
                float gv = ftanh(acc[q + 8][r]);
                float ov = fsig(acc[q + 12][r]);
                float cn = __builtin_fmaf(fv, cst[r][q], iv * gv);
                cst[r][q] = cn;
                hreg[r][q] = ov * ftanh(cn);
            }
        __syncthreads();
#pragma unroll
        for (int r = 0; r < 4; ++r)
#pragma unroll
            for (int q = 0; q < 4; ++q)
                hls[(4 * lg + r) * 72 + 16 * q + lr] = f2b(hreg[r][q]);
        __syncthreads();
    }
#pragma unroll
    for (int r = 0; r < 4; ++r)
#pragma unroll
        for (int q = 0; q < 4; ++q)
            hf[(4 * lg + r) * 65 + 16 * q + lr] = hreg[r][q];
    __syncthreads();
    {
        int r = l & 15, p = l >> 4;
        float hid[8];
#pragma unroll
        for (int q = 0; q < 8; ++q) hid[q] = bo1[8 * p + q];
        for (int j = 0; j < 64; ++j) {
            float hv = hf[r * 65 + j];
#pragma unroll
            for (int q = 0; q < 8; ++q) hid[q] += hv * wo1[j * 32 + 8 * p + q];
        }
        float po = 0.f;
#pragma unroll
        for (int q = 0; q < 8; ++q) po += fmaxf(hid[q], 0.f) * wo2[8 * p + q];
        po += __shfl_xor(po, 16);
        po += __shfl_xor(po, 32);
        if (p == 0) out[m0 + r] = po + bo2[0];
    }
}

extern "C" void kernel_launch(void* const* d_in, const int* in_sizes, int n_in,
                              void* d_out, int out_size, void* d_ws, size_t ws_size,
                              hipStream_t stream) {
    const float* x    = (const float*)d_in[0];
    const int*   adj  = (const int*)d_in[1];
    const float* W1   = (const float*)d_in[2];
    const float* a1   = (const float*)d_in[3];
    const float* W2   = (const float*)d_in[4];
    const float* a2   = (const float*)d_in[5];
    const float* W_ih = (const float*)d_in[6];
    const float* W_hh = (const float*)d_in[7];
    const float* b_ih = (const float*)d_in[8];
    const float* b_hh = (const float*)d_in[9];
    const float* Wo1  = (const float*)d_in[10];
    const float* bo1  = (const float*)d_in[11];
    const float* Wo2  = (const float*)d_in[12];
    const float* bo2  = (const float*)d_in[13];
    float* out = (float*)d_out;

    char* w = (char*)d_ws;
    const size_t SLOT = (size_t)8388608 * sizeof(u16);   // 16.78 MB
    u16* A  = (u16*)w;
    u16* Bf = (u16*)(w + SLOT);
    u16* C  = (u16*)(w + 2 * SLOT);
    char* sm = w + 3 * SLOT;
    float* s1s = (float*)sm;
    float* s1d = s1s + 65536;
    float* s2s = s1d + 65536;
    float* s2d = s2s + 65536;
    u32* BM  = (u32*)(s2d + 65536);      // 131072 words (512 KB)
    u16* W1T = (u16*)(BM + 131072);      // 4096
    u16* W2T = W1T + 4096;               // 16384
    u16* WihB = W2T + 16384;             // 32768
    u16* WhhB = WihB + 32768;            // 16384
    float* BS = (float*)(WhhB + 16384);  // 256
    u16* Gx = Bf;                        // Bf dead after projB; Gx spans Bf..C (33.55 MB)

    k_pre<<<64, 256, 0, stream>>>(W1, W2, W_ih, W_hh, b_ih, b_hh, W1T, W2T, WihB, WhhB, BS);
    k_mask<<<256, 256, 0, stream>>>(adj, (unsigned long long*)BM);
    k_projA<<<1024, 256, 0, stream>>>(x, W1T, a1, A, s1s, s1d);
    k_attn<false><<<512, 256, 0, stream>>>(A, s1s, s1d, BM, Bf, nullptr, nullptr, nullptr);
    k_projB<<<1024, 256, 0, stream>>>(Bf, W2T, a2, C, s2s, s2d);
    k_attn<true><<<512, 256, 0, stream>>>(C, s2s, s2d, BM, nullptr, WihB, BS, Gx);
    k_lstm<<<256, 64, 0, stream>>>(Gx, WhhB, Wo1, bo1, Wo2, bo2, out);
}